// Round 2
// baseline (39353.412 us; speedup 1.0000x reference)
//
#include <hip/hip_runtime.h>
#include <hip/hip_bf16.h>

typedef short short8 __attribute__((ext_vector_type(8)));
typedef float f32x4 __attribute__((ext_vector_type(4)));
typedef _Float16 f16;

#define TT 512
#define BB 64
#define FF 51
#define HH 512

// workspace layout (bytes)
#define OFF_CNT 0              // counters (4KB)
#define OFF_H   4096           // 2 groups * 4 arrays * [2][32][512] fp16 = 512KB
#define OFF_XHI 528384         // x hi fp16 padded [64][512][64] = 4MB
#define OFF_XLO 4722688        // x lo fp16 = 4MB
#define OFF_D1  8916992        // dec layer1 ys [64][512][512] fp16 = 32MB
// total ~40.5MB

__device__ __forceinline__ unsigned short h2u(f16 h) { return __builtin_bit_cast(unsigned short, h); }
__device__ __forceinline__ float sigm(float x) { return 1.f / (1.f + __expf(-x)); }
__device__ __forceinline__ float tanh_(float x) { return 1.f - 2.f / (__expf(2.f * x) + 1.f); }

__device__ __forceinline__ f32x4 mfmaH(short8 a, short8 b, f32x4 c) {
  asm("v_mfma_f32_16x16x32_f16 %0, %1, %2, %0" : "+v"(c) : "v"(a), "v"(b));
  return c;
}

__global__ void init_kernel(const float* __restrict__ x, unsigned short* __restrict__ xhi,
                            unsigned short* __restrict__ xlo, unsigned short* __restrict__ hb,
                            int* __restrict__ cnt) {
  int tid = blockIdx.x * 256 + threadIdx.x;
  if (tid < 1024) cnt[tid] = 0;
  for (int i = tid; i < 262144; i += gridDim.x * 256) hb[i] = 0;   // all h hi/lo, both groups
  for (int i = tid; i < BB * TT * 64; i += gridDim.x * 256) {
    int f = i & 63;
    int bt = i >> 6;
    float v = (f < FF) ? x[bt * FF + f] : 0.f;
    f16 hi = (f16)v;
    f16 lo = (f16)(v - (float)hi);
    xhi[i] = h2u(hi);
    xlo[i] = h2u(lo);
  }
}

__global__ __launch_bounds__(256, 1)
void lstm_kernel(const float* __restrict__ wih0e, const float* __restrict__ whh0e,
                 const float* __restrict__ bih0e, const float* __restrict__ bhh0e,
                 const float* __restrict__ wih1e, const float* __restrict__ whh1e,
                 const float* __restrict__ bih1e, const float* __restrict__ bhh1e,
                 const float* __restrict__ wih0d, const float* __restrict__ whh0d,
                 const float* __restrict__ bih0d, const float* __restrict__ bhh0d,
                 const float* __restrict__ wih1d, const float* __restrict__ whh1d,
                 const float* __restrict__ bih1d, const float* __restrict__ bhh1d,
                 unsigned short* hb, const unsigned short* xhi, const unsigned short* xlo,
                 unsigned short* d1, int* cnt) {
  extern __shared__ char smem[];
  // W hi: [m][16][512] fp16 swizzled at m*16384 ; W lo at 49152+m*16384 (m: 0=hh0,1=ih1,2=hh1)
  char* wXhi = smem + 98304;               // [16][64] fp16
  char* wXlo = smem + 100352;
  float* bias = (float*)(smem + 102400);   // [2][16]
  float* gbuf = (float*)(smem + 102592);   // [18][16][17] fp32
  char* sh0hi = smem + 122176;             // [32][128] fp16 swizzled (K-chunk staging)
  char* sh0lo = smem + 130368;
  char* sh1hi = smem + 138560;
  char* sh1lo = smem + 146752;             // ends 154944

  const int tid = threadIdx.x;
  const int bid = blockIdx.x;
  const int group = bid & 1;     // 2 groups of 128 blocks
  const int slot = bid >> 1;     // 0..127 : owns 4 H-columns
  const int hc0 = slot * 4;
  const int wave = tid >> 6;
  const int lane = tid & 63;
  const int lr = lane & 15;      // fragment row/col index
  const int lq = lane >> 4;      // k-quarter
  const int bbase = group * 32;  // 32 chains per group

  unsigned short* hbg = hb + group * 131072;
  unsigned short* h0hi = hbg;                 // each [2][32][512] fp16
  unsigned short* h0lo = hbg + 32768;
  unsigned short* h1hi = hbg + 65536;
  unsigned short* h1lo = hbg + 98304;
  int* mycnt = cnt + group * 32;

  // elementwise ownership (persistent): thread -> (layer, chain, hcol); c in register
  const int eL = tid >> 7;
  const int eCi = (tid >> 2) & 31;
  const int eHc = tid & 3;
  float creg = 0.f;

  for (int phase = 0; phase < 2; ++phase) {
    const float* Wih0 = phase ? wih0d : wih0e;
    const float* Whh0 = phase ? whh0d : whh0e;
    const float* Wih1 = phase ? wih1d : wih1e;
    const float* Whh1 = phase ? whh1d : whh1e;
    // ---- load weight slices as fp16 hi+lo, swizzled ----
    for (int m = 0; m < 3; ++m) {
      const float* W = (m == 0) ? Whh0 : ((m == 1) ? Wih1 : Whh1);
      char* dHi = smem + m * 16384;
      char* dLo = smem + 49152 + m * 16384;
#pragma unroll
      for (int it = 0; it < 4; ++it) {
        int task = tid + it * 256;       // 0..1023
        int c8 = task & 63;              // 8-float chunk
        int r = task >> 6;               // local row 0..15 : gate r>>2, col hc0+(r&3)
        int grow = (r >> 2) * HH + hc0 + (r & 3);
        const float* src = W + grow * HH + c8 * 8;
        alignas(16) unsigned short thi[8], tlo[8];
#pragma unroll
        for (int e = 0; e < 8; ++e) {
          float v = src[e];
          f16 h = (f16)v;
          thi[e] = h2u(h);
          tlo[e] = h2u((f16)(v - (float)h));
        }
        int off = r * 1024 + ((c8 * 16) ^ ((r & 7) << 4));
        *(short8*)(dHi + off) = *(const short8*)thi;
        *(short8*)(dLo + off) = *(const short8*)tlo;
      }
    }
    if (tid < 128) {  // w_ih0 slice [16][64] hi+lo (features 51 padded)
      int c8 = tid & 7, r = tid >> 3;
      int grow = (r >> 2) * HH + hc0 + (r & 3);
      const float* src = Wih0 + grow * FF;
      alignas(16) unsigned short thi[8], tlo[8];
#pragma unroll
      for (int e = 0; e < 8; ++e) {
        int f = c8 * 8 + e;
        float v = (f < FF) ? src[f] : 0.f;
        f16 h = (f16)v;
        thi[e] = h2u(h);
        tlo[e] = h2u((f16)(v - (float)h));
      }
      int off = r * 128 + ((c8 * 16) ^ ((r & 7) << 4));
      *(short8*)(wXhi + off) = *(const short8*)thi;
      *(short8*)(wXlo + off) = *(const short8*)tlo;
    }
    if (tid < 32) {
      int L = tid >> 4, r = tid & 15;
      int grow = (r >> 2) * HH + hc0 + (r & 3);
      const float* bi = L ? (phase ? bih1d : bih1e) : (phase ? bih0d : bih0e);
      const float* bh = L ? (phase ? bhh1d : bhh1e) : (phase ? bhh0d : bhh0e);
      bias[L * 16 + r] = bi[grow] + bh[grow];
    }
    __syncthreads();

    // iteration k: layer0 does step k (k<TT); layer1 does step k-1 (k>=1)
    for (int k = 0; k <= TT; ++k) {
      const bool act0 = (k < TT), act1 = (k >= 1);
      const unsigned short* s0hiG = h0hi + ((k + 1) & 1) * 16384;
      const unsigned short* s0loG = h0lo + ((k + 1) & 1) * 16384;
      const unsigned short* s1hiG = h1hi + (k & 1) * 16384;
      const unsigned short* s1loG = h1lo + (k & 1) * 16384;

      f32x4 acc[5];
#pragma unroll
      for (int i = 0; i < 5; ++i) acc[i] = (f32x4){0.f, 0.f, 0.f, 0.f};

      // x contribution (layer0 jobs j<6), A straight from global
      int xrow = phase ? (k == 0 ? TT - 1 : k - 1) : k;
#pragma unroll
      for (int i = 0; i < 5; ++i) {
        int j = wave + 4 * i;
        if (j < 6 && act0) {
          int t = j >> 1, mt = j & 1;
          const unsigned short* xa = (t == 2 ? xlo : xhi) +
              ((bbase + mt * 16 + lr) * TT + xrow) * 64 + lq * 8;
          const char* xb = (t == 1) ? wXlo : wXhi;
#pragma unroll
          for (int kk = 0; kk < 2; ++kk) {
            short8 a = *(const short8*)(xa + kk * 32);
            short8 b = *(const short8*)(xb + lr * 128 + ((kk * 64 + lq * 16) ^ ((lr & 7) << 4)));
            acc[i] = mfmaH(a, b, acc[i]);
          }
        }
      }

      // K-chunked staging + MFMA jobs. 18 jobs: [0,6)=hh0, [6,12)=ih1, [12,18)=hh1;
      // within sextet: jj=t*2+mt, t: 0=hi*Whi 1=hi*Wlo 2=lo*Whi
      for (int c = 0; c < 4; ++c) {
#pragma unroll
        for (int i2 = 0; i2 < 2; ++i2) {
          int task = tid + i2 * 256;          // 0..511
          int chain = task >> 4, k8 = task & 15;
          int srcOff = chain * 512 + c * 128 + k8 * 8;
          int dst = chain * 256 + ((k8 * 16) ^ ((chain & 7) << 4));
          *(short8*)(sh0hi + dst) = *(const short8*)(s0hiG + srcOff);
          *(short8*)(sh0lo + dst) = *(const short8*)(s0loG + srcOff);
          *(short8*)(sh1hi + dst) = *(const short8*)(s1hiG + srcOff);
          *(short8*)(sh1lo + dst) = *(const short8*)(s1loG + srcOff);
        }
        __syncthreads();
#pragma unroll
        for (int i = 0; i < 5; ++i) {
          int j = wave + 4 * i;
          if (j < 18) {
            bool act = (j < 6) ? act0 : act1;
            if (act) {
              int jj = (j < 6) ? j : ((j < 12) ? j - 6 : j - 12);
              int t = jj >> 1, mt = jj & 1;
              const char* A = (j < 12) ? (t == 2 ? sh0lo : sh0hi) : (t == 2 ? sh1lo : sh1hi);
              int m = (j < 6) ? 0 : ((j < 12) ? 1 : 2);
              const char* Bp = (t == 1) ? (smem + 49152 + m * 16384) : (smem + m * 16384);
              int arow = mt * 16 + lr;
              const char* Abase = A + arow * 256;
              int aswz = (arow & 7) << 4;
              const char* Bbase = Bp + lr * 1024;
              int bswz = (lr & 7) << 4;
#pragma unroll
              for (int kk = 0; kk < 4; ++kk) {
                short8 a = *(const short8*)(Abase + ((kk * 64 + lq * 16) ^ aswz));
                short8 b = *(const short8*)(Bbase + ((c * 256 + kk * 64 + lq * 16) ^ bswz));
                acc[i] = mfmaH(a, b, acc[i]);
              }
            }
          }
        }
        __syncthreads();
      }

      // publish fp32 partials: gbuf[j][chain(=lq*4+e)][row(=lr)]
#pragma unroll
      for (int i = 0; i < 5; ++i) {
        int j = wave + 4 * i;
        if (j < 18) {
#pragma unroll
          for (int e = 0; e < 4; ++e)
            gbuf[j * 272 + (lq * 4 + e) * 17 + lr] = acc[i][e];
        }
      }
      __syncthreads();

      // elementwise cell update: 1 (layer,chain,hcol) per thread
      {
        bool act = eL ? act1 : act0;
        if (act) {
          int s = eL ? (k - 1) : k;
          int mt = eCi >> 4, cl = eCi & 15;
          float g[4];
#pragma unroll
          for (int q = 0; q < 4; ++q) {
            int ro = q * 4 + eHc;
            float v = bias[eL * 16 + ro];
            if (eL == 0) {
#pragma unroll
              for (int t = 0; t < 3; ++t) v += gbuf[(t * 2 + mt) * 272 + cl * 17 + ro];
            } else {
#pragma unroll
              for (int u = 0; u < 6; ++u) v += gbuf[(6 + u * 2 + mt) * 272 + cl * 17 + ro];
            }
            g[q] = v;
          }
          creg = sigm(g[1]) * creg + sigm(g[0]) * tanh_(g[2]);
          float h = sigm(g[3]) * tanh_(creg);
          f16 hhv = (f16)h;
          f16 hlv = (f16)(h - (float)hhv);
          int off = (s & 1) * 16384 + eCi * 512 + hc0 + eHc;
          if (eL == 0) { h0hi[off] = h2u(hhv); h0lo[off] = h2u(hlv); }
          else {
            h1hi[off] = h2u(hhv); h1lo[off] = h2u(hlv);
            if (phase) d1[((bbase + eCi) * TT + s) * HH + hc0 + eHc] = h2u(hhv);
          }
        }
      }
      __syncthreads();

      // group barrier (release add -> relaxed spin -> acquire fence)
      if (tid == 0) {
        __hip_atomic_fetch_add(mycnt, 1, __ATOMIC_RELEASE, __HIP_MEMORY_SCOPE_AGENT);
        int target = 128 * (phase * (TT + 1) + k + 1);
        long guard = 0;
        while (__hip_atomic_load(mycnt, __ATOMIC_RELAXED, __HIP_MEMORY_SCOPE_AGENT) < target) {
          if (++guard > (1L << 26)) break;   // anti-deadlock bail
        }
      }
      __syncthreads();
      __threadfence();
    }
  }
}

__global__ __launch_bounds__(256, 1)
void outproj_kernel(const unsigned short* __restrict__ d1, const float* __restrict__ out_w,
                    const float* __restrict__ out_b, float* __restrict__ out) {
  extern __shared__ char smem[];
  const int tid = threadIdx.x;
#pragma unroll
  for (int i = 0; i < 16; ++i) {  // out_w [51][512] -> LDS [64][512] fp16 swizzled
    int task = tid + i * 256;
    int c8 = task & 63;
    int r = task >> 6;
    alignas(16) unsigned short tmp[8];
    if (r < FF) {
      const float* src = out_w + r * HH + c8 * 8;
#pragma unroll
      for (int e = 0; e < 8; ++e) tmp[e] = h2u((f16)src[e]);
    } else {
#pragma unroll
      for (int e = 0; e < 8; ++e) tmp[e] = 0;
    }
    *(short8*)(smem + r * 1024 + ((c8 * 16) ^ ((r & 7) << 4))) = *(const short8*)tmp;
  }
  __syncthreads();
  const int wave = tid >> 6, lane = tid & 63;
  const int lr = lane & 15, lq = lane >> 4;
  const int r0 = blockIdx.x * 64 + wave * 16;   // row in [B*T, H] view of d1
  f32x4 acc0 = {0.f, 0.f, 0.f, 0.f}, acc1 = acc0, acc2 = acc0, acc3 = acc0;
  const unsigned short* ap = d1 + (r0 + lr) * HH + lq * 8;
#pragma unroll
  for (int kk = 0; kk < 16; ++kk) {
    short8 a = *(const short8*)(ap + kk * 32);
    int kb = kk * 64 + lq * 16;
    acc0 = mfmaH(a, *(const short8*)(smem + (0 + lr) * 1024 + (kb ^ ((lr & 7) << 4))), acc0);
    acc1 = mfmaH(a, *(const short8*)(smem + (16 + lr) * 1024 + (kb ^ ((lr & 7) << 4))), acc1);
    acc2 = mfmaH(a, *(const short8*)(smem + (32 + lr) * 1024 + (kb ^ ((lr & 7) << 4))), acc2);
    acc3 = mfmaH(a, *(const short8*)(smem + (48 + lr) * 1024 + (kb ^ ((lr & 7) << 4))), acc3);
  }
  f32x4 accs[4] = {acc0, acc1, acc2, acc3};
#pragma unroll
  for (int nt = 0; nt < 4; ++nt) {
    int col = nt * 16 + lr;
    if (col < FF) {
      float bb = out_b[col];
#pragma unroll
      for (int e = 0; e < 4; ++e) {
        int row = r0 + lq * 4 + e;
        out[row * FF + col] = accs[nt][e] + bb;
      }
    }
  }
}

extern "C" void kernel_launch(void* const* d_in, const int* in_sizes, int n_in,
                              void* d_out, int out_size, void* d_ws, size_t ws_size,
                              hipStream_t stream) {
  const float* x = (const float*)d_in[0];
  const float* ew_ih0 = (const float*)d_in[1];
  const float* ew_hh0 = (const float*)d_in[2];
  const float* eb_ih0 = (const float*)d_in[3];
  const float* eb_hh0 = (const float*)d_in[4];
  const float* ew_ih1 = (const float*)d_in[5];
  const float* ew_hh1 = (const float*)d_in[6];
  const float* eb_ih1 = (const float*)d_in[7];
  const float* eb_hh1 = (const float*)d_in[8];
  const float* dw_ih0 = (const float*)d_in[9];
  const float* dw_hh0 = (const float*)d_in[10];
  const float* db_ih0 = (const float*)d_in[11];
  const float* db_hh0 = (const float*)d_in[12];
  const float* dw_ih1 = (const float*)d_in[13];
  const float* dw_hh1 = (const float*)d_in[14];
  const float* db_ih1 = (const float*)d_in[15];
  const float* db_hh1 = (const float*)d_in[16];
  const float* out_w = (const float*)d_in[17];
  const float* out_b = (const float*)d_in[18];

  char* ws = (char*)d_ws;
  int* cnt = (int*)(ws + OFF_CNT);
  unsigned short* hb = (unsigned short*)(ws + OFF_H);
  unsigned short* xhi = (unsigned short*)(ws + OFF_XHI);
  unsigned short* xlo = (unsigned short*)(ws + OFF_XLO);
  unsigned short* d1 = (unsigned short*)(ws + OFF_D1);

  (void)hipFuncSetAttribute((const void*)lstm_kernel, hipFuncAttributeMaxDynamicSharedMemorySize, 154944);
  (void)hipFuncSetAttribute((const void*)outproj_kernel, hipFuncAttributeMaxDynamicSharedMemorySize, 65536);

  init_kernel<<<1024, 256, 0, stream>>>(x, xhi, xlo, hb, cnt);
  lstm_kernel<<<256, 256, 154944, stream>>>(ew_ih0, ew_hh0, eb_ih0, eb_hh0,
                                            ew_ih1, ew_hh1, eb_ih1, eb_hh1,
                                            dw_ih0, dw_hh0, db_ih0, db_hh0,
                                            dw_ih1, dw_hh1, db_ih1, db_hh1,
                                            hb, xhi, xlo, d1, cnt);
  outproj_kernel<<<512, 256, 65536, stream>>>(d1, out_w, out_b, (float*)d_out);
}

// Round 8
// 36880.618 us; speedup vs baseline: 1.0670x; 1.0670x over previous
//
#include <hip/hip_runtime.h>
#include <hip/hip_bf16.h>

typedef short short8 __attribute__((ext_vector_type(8)));
typedef float f32x4 __attribute__((ext_vector_type(4)));
typedef _Float16 f16;

#define TT 512
#define BB 64
#define FF 51
#define HH 512

// workspace layout (bytes)
#define OFF_CNT 0              // counters: 2 groups * 256 ints (8 spread sub-counters / group)
#define OFF_H   4096           // 2 groups * 4 arrays * [2][32][512] fp16 = 512KB
#define OFF_XHI 528384         // x hi fp16 padded [64][512][64] = 4MB
#define OFF_XLO 4722688        // x lo fp16 = 4MB
#define OFF_D1  8916992        // dec layer1 ys [64][512][512] fp16 = 32MB

__device__ __forceinline__ unsigned short h2u(f16 h) { return __builtin_bit_cast(unsigned short, h); }
__device__ __forceinline__ float sigm(float x) { return 1.f / (1.f + __expf(-x)); }
__device__ __forceinline__ float tanh_(float x) { return 1.f - 2.f / (__expf(2.f * x) + 1.f); }

__device__ __forceinline__ f32x4 mfmaH(short8 a, short8 b, f32x4 c) {
  asm("v_mfma_f32_16x16x32_f16 %0, %1, %2, %0" : "+v"(c) : "v"(a), "v"(b));
  return c;
}

__global__ void init_kernel(const float* __restrict__ x, unsigned short* __restrict__ xhi,
                            unsigned short* __restrict__ xlo, unsigned short* __restrict__ hb,
                            int* __restrict__ cnt) {
  int tid = blockIdx.x * 256 + threadIdx.x;
  if (tid < 1024) cnt[tid] = 0;
  for (int i = tid; i < 262144; i += gridDim.x * 256) hb[i] = 0;   // all h hi/lo, both groups
  for (int i = tid; i < BB * TT * 64; i += gridDim.x * 256) {
    int f = i & 63;
    int bt = i >> 6;
    float v = (f < FF) ? x[bt * FF + f] : 0.f;
    f16 hi = (f16)v;
    f16 lo = (f16)(v - (float)hi);
    xhi[i] = h2u(hi);
    xlo[i] = h2u(lo);
  }
}

__global__ __launch_bounds__(256, 1)
void lstm_kernel(const float* __restrict__ wih0e, const float* __restrict__ whh0e,
                 const float* __restrict__ bih0e, const float* __restrict__ bhh0e,
                 const float* __restrict__ wih1e, const float* __restrict__ whh1e,
                 const float* __restrict__ bih1e, const float* __restrict__ bhh1e,
                 const float* __restrict__ wih0d, const float* __restrict__ whh0d,
                 const float* __restrict__ bih0d, const float* __restrict__ bhh0d,
                 const float* __restrict__ wih1d, const float* __restrict__ whh1d,
                 const float* __restrict__ bih1d, const float* __restrict__ bhh1d,
                 unsigned short* hb, const unsigned short* xhi, const unsigned short* xlo,
                 unsigned short* d1, int* cnt) {
  extern __shared__ char smem[];
  // W hi: [m][16][512] fp16 swizzled at m*16384 ; W lo at 49152+m*16384 (m: 0=hh0,1=ih1,2=hh1)
  char* wXhi = smem + 98304;               // [16][64] fp16
  char* wXlo = smem + 100352;
  float* bias = (float*)(smem + 102400);   // [2][16]
  float* gbuf = (float*)(smem + 102592);   // [18][16][17] fp32
  char* sh0hi = smem + 122176;             // [32][128] fp16 swizzled (K-chunk staging)
  char* sh0lo = smem + 130368;
  char* sh1hi = smem + 138560;
  char* sh1lo = smem + 146752;             // ends 154944

  const int tid = threadIdx.x;
  const int bid = blockIdx.x;
  const int group = bid & 1;     // 2 groups of 128 blocks
  const int slot = bid >> 1;     // 0..127 : owns 4 H-columns
  const int hc0 = slot * 4;
  const int wave = tid >> 6;
  const int lane = tid & 63;
  const int lr = lane & 15;      // fragment row/col index
  const int lq = lane >> 4;      // k-quarter
  const int bbase = group * 32;  // 32 chains per group

  unsigned short* hbg = hb + group * 131072;
  unsigned short* h0hi = hbg;                 // each [2][32][512] fp16
  unsigned short* h0lo = hbg + 32768;
  unsigned short* h1hi = hbg + 65536;
  unsigned short* h1lo = hbg + 98304;
  int* mycnt = cnt + group * 256;             // 8 sub-counters at stride 32 ints

  // elementwise ownership (persistent): thread -> (layer, chain, hcol); c in register
  const int eL = tid >> 7;
  const int eCi = (tid >> 2) & 31;
  const int eHc = tid & 3;
  float creg = 0.f;

  for (int phase = 0; phase < 2; ++phase) {
    const float* Wih0 = phase ? wih0d : wih0e;
    const float* Whh0 = phase ? whh0d : whh0e;
    const float* Wih1 = phase ? wih1d : wih1e;
    const float* Whh1 = phase ? whh1d : whh1e;
    // ---- load weight slices as fp16 hi+lo, swizzled ----
    for (int m = 0; m < 3; ++m) {
      const float* W = (m == 0) ? Whh0 : ((m == 1) ? Wih1 : Whh1);
      char* dHi = smem + m * 16384;
      char* dLo = smem + 49152 + m * 16384;
#pragma unroll
      for (int it = 0; it < 4; ++it) {
        int task = tid + it * 256;       // 0..1023
        int c8 = task & 63;              // 8-float chunk
        int r = task >> 6;               // local row 0..15 : gate r>>2, col hc0+(r&3)
        int grow = (r >> 2) * HH + hc0 + (r & 3);
        const float* src = W + grow * HH + c8 * 8;
        alignas(16) unsigned short thi[8], tlo[8];
#pragma unroll
        for (int e = 0; e < 8; ++e) {
          float v = src[e];
          f16 h = (f16)v;
          thi[e] = h2u(h);
          tlo[e] = h2u((f16)(v - (float)h));
        }
        int off = r * 1024 + ((c8 * 16) ^ ((r & 7) << 4));
        *(short8*)(dHi + off) = *(const short8*)thi;
        *(short8*)(dLo + off) = *(const short8*)tlo;
      }
    }
    if (tid < 128) {  // w_ih0 slice [16][64] hi+lo (features 51 padded)
      int c8 = tid & 7, r = tid >> 3;
      int grow = (r >> 2) * HH + hc0 + (r & 3);
      const float* src = Wih0 + grow * FF;
      alignas(16) unsigned short thi[8], tlo[8];
#pragma unroll
      for (int e = 0; e < 8; ++e) {
        int f = c8 * 8 + e;
        float v = (f < FF) ? src[f] : 0.f;
        f16 h = (f16)v;
        thi[e] = h2u(h);
        tlo[e] = h2u((f16)(v - (float)h));
      }
      int off = r * 128 + ((c8 * 16) ^ ((r & 7) << 4));
      *(short8*)(wXhi + off) = *(const short8*)thi;
      *(short8*)(wXlo + off) = *(const short8*)tlo;
    }
    if (tid < 32) {
      int L = tid >> 4, r = tid & 15;
      int grow = (r >> 2) * HH + hc0 + (r & 3);
      const float* bi = L ? (phase ? bih1d : bih1e) : (phase ? bih0d : bih0e);
      const float* bh = L ? (phase ? bhh1d : bhh1e) : (phase ? bhh0d : bhh0e);
      bias[L * 16 + r] = bi[grow] + bh[grow];
    }
    __syncthreads();

    // iteration k: layer0 does step k (k<TT); layer1 does step k-1 (k>=1)
    for (int k = 0; k <= TT; ++k) {
      const bool act0 = (k < TT), act1 = (k >= 1);
      const unsigned short* s0hiG = h0hi + ((k + 1) & 1) * 16384;
      const unsigned short* s0loG = h0lo + ((k + 1) & 1) * 16384;
      const unsigned short* s1hiG = h1hi + (k & 1) * 16384;
      const unsigned short* s1loG = h1lo + (k & 1) * 16384;

      f32x4 acc[5];
#pragma unroll
      for (int i = 0; i < 5; ++i) acc[i] = (f32x4){0.f, 0.f, 0.f, 0.f};

      // x contribution (layer0 jobs j<6), A straight from global
      int xrow = phase ? (k == 0 ? TT - 1 : k - 1) : k;
#pragma unroll
      for (int i = 0; i < 5; ++i) {
        int j = wave + 4 * i;
        if (j < 6 && act0) {
          int t = j >> 1, mt = j & 1;
          const unsigned short* xa = (t == 2 ? xlo : xhi) +
              ((bbase + mt * 16 + lr) * TT + xrow) * 64 + lq * 8;
          const char* xb = (t == 1) ? wXlo : wXhi;
#pragma unroll
          for (int kk = 0; kk < 2; ++kk) {
            short8 a = *(const short8*)(xa + kk * 32);
            short8 b = *(const short8*)(xb + lr * 128 + ((kk * 64 + lq * 16) ^ ((lr & 7) << 4)));
            acc[i] = mfmaH(a, b, acc[i]);
          }
        }
      }

      // K-chunked staging + MFMA jobs. 18 jobs: [0,6)=hh0, [6,12)=ih1, [12,18)=hh1;
      // within sextet: jj=t*2+mt, t: 0=hi*Whi 1=hi*Wlo 2=lo*Whi
      for (int c = 0; c < 4; ++c) {
#pragma unroll
        for (int i2 = 0; i2 < 2; ++i2) {
          int task = tid + i2 * 256;          // 0..511
          int chain = task >> 4, k8 = task & 15;
          int srcOff = chain * 512 + c * 128 + k8 * 8;
          int dst = chain * 256 + ((k8 * 16) ^ ((chain & 7) << 4));
          *(short8*)(sh0hi + dst) = *(const short8*)(s0hiG + srcOff);
          *(short8*)(sh0lo + dst) = *(const short8*)(s0loG + srcOff);
          *(short8*)(sh1hi + dst) = *(const short8*)(s1hiG + srcOff);
          *(short8*)(sh1lo + dst) = *(const short8*)(s1loG + srcOff);
        }
        __syncthreads();
#pragma unroll
        for (int i = 0; i < 5; ++i) {
          int j = wave + 4 * i;
          if (j < 18) {
            bool act = (j < 6) ? act0 : act1;
            if (act) {
              int jj = (j < 6) ? j : ((j < 12) ? j - 6 : j - 12);
              int t = jj >> 1, mt = jj & 1;
              const char* A = (j < 12) ? (t == 2 ? sh0lo : sh0hi) : (t == 2 ? sh1lo : sh1hi);
              int m = (j < 6) ? 0 : ((j < 12) ? 1 : 2);
              const char* Bp = (t == 1) ? (smem + 49152 + m * 16384) : (smem + m * 16384);
              int arow = mt * 16 + lr;
              const char* Abase = A + arow * 256;
              int aswz = (arow & 7) << 4;
              const char* Bbase = Bp + lr * 1024;
              int bswz = (lr & 7) << 4;
#pragma unroll
              for (int kk = 0; kk < 4; ++kk) {
                short8 a = *(const short8*)(Abase + ((kk * 64 + lq * 16) ^ aswz));
                short8 b = *(const short8*)(Bbase + ((c * 256 + kk * 64 + lq * 16) ^ bswz));
                acc[i] = mfmaH(a, b, acc[i]);
              }
            }
          }
        }
        __syncthreads();
      }

      // publish fp32 partials: gbuf[j][chain(=lq*4+e)][row(=lr)]
#pragma unroll
      for (int i = 0; i < 5; ++i) {
        int j = wave + 4 * i;
        if (j < 18) {
#pragma unroll
          for (int e = 0; e < 4; ++e)
            gbuf[j * 272 + (lq * 4 + e) * 17 + lr] = acc[i][e];
        }
      }
      __syncthreads();

      // elementwise cell update: 1 (layer,chain,hcol) per thread
      {
        bool act = eL ? act1 : act0;
        if (act) {
          int s = eL ? (k - 1) : k;
          int mt = eCi >> 4, cl = eCi & 15;
          float g[4];
#pragma unroll
          for (int q = 0; q < 4; ++q) {
            int ro = q * 4 + eHc;
            float v = bias[eL * 16 + ro];
            if (eL == 0) {
#pragma unroll
              for (int t = 0; t < 3; ++t) v += gbuf[(t * 2 + mt) * 272 + cl * 17 + ro];
            } else {
#pragma unroll
              for (int u = 0; u < 6; ++u) v += gbuf[(6 + u * 2 + mt) * 272 + cl * 17 + ro];
            }
            g[q] = v;
          }
          creg = sigm(g[1]) * creg + sigm(g[0]) * tanh_(g[2]);
          float h = sigm(g[3]) * tanh_(creg);
          f16 hhv = (f16)h;
          f16 hlv = (f16)(h - (float)hhv);
          int off = (s & 1) * 16384 + eCi * 512 + hc0 + eHc;
          if (eL == 0) { h0hi[off] = h2u(hhv); h0lo[off] = h2u(hlv); }
          else {
            h1hi[off] = h2u(hhv); h1lo[off] = h2u(hlv);
            if (phase) d1[((bbase + eCi) * TT + s) * HH + hc0 + eHc] = h2u(hhv);
          }
        }
      }
      __syncthreads();

      // group barrier (R2 protocol; ONLY change: 8 spread sub-counters instead of 1)
      if (tid == 0) {
        __hip_atomic_fetch_add(mycnt + (slot & 7) * 32, 1, __ATOMIC_RELEASE, __HIP_MEMORY_SCOPE_AGENT);
        int target = 128 * (phase * (TT + 1) + k + 1);
        long guard = 0;
        for (;;) {
          int sum = 0;
#pragma unroll
          for (int jj = 0; jj < 8; ++jj)
            sum += __hip_atomic_load(mycnt + jj * 32, __ATOMIC_RELAXED, __HIP_MEMORY_SCOPE_AGENT);
          if (sum >= target) break;
          if (++guard > (1L << 26)) break;   // anti-deadlock bail (turns hang into wrong-answer)
        }
      }
      __syncthreads();
      __threadfence();
    }
  }
}

__global__ __launch_bounds__(256, 1)
void outproj_kernel(const unsigned short* __restrict__ d1, const float* __restrict__ out_w,
                    const float* __restrict__ out_b, float* __restrict__ out) {
  extern __shared__ char smem[];
  const int tid = threadIdx.x;
#pragma unroll
  for (int i = 0; i < 16; ++i) {  // out_w [51][512] -> LDS [64][512] fp16 swizzled
    int task = tid + i * 256;
    int c8 = task & 63;
    int r = task >> 6;
    alignas(16) unsigned short tmp[8];
    if (r < FF) {
      const float* src = out_w + r * HH + c8 * 8;
#pragma unroll
      for (int e = 0; e < 8; ++e) tmp[e] = h2u((f16)src[e]);
    } else {
#pragma unroll
      for (int e = 0; e < 8; ++e) tmp[e] = 0;
    }
    *(short8*)(smem + r * 1024 + ((c8 * 16) ^ ((r & 7) << 4))) = *(const short8*)tmp;
  }
  __syncthreads();
  const int wave = tid >> 6, lane = tid & 63;
  const int lr = lane & 15, lq = lane >> 4;
  const int r0 = blockIdx.x * 64 + wave * 16;   // row in [B*T, H] view of d1
  f32x4 acc0 = {0.f, 0.f, 0.f, 0.f}, acc1 = acc0, acc2 = acc0, acc3 = acc0;
  const unsigned short* ap = d1 + (r0 + lr) * HH + lq * 8;
#pragma unroll
  for (int kk = 0; kk < 16; ++kk) {
    short8 a = *(const short8*)(ap + kk * 32);
    int kb = kk * 64 + lq * 16;
    acc0 = mfmaH(a, *(const short8*)(smem + (0 + lr) * 1024 + (kb ^ ((lr & 7) << 4))), acc0);
    acc1 = mfmaH(a, *(const short8*)(smem + (16 + lr) * 1024 + (kb ^ ((lr & 7) << 4))), acc1);
    acc2 = mfmaH(a, *(const short8*)(smem + (32 + lr) * 1024 + (kb ^ ((lr & 7) << 4))), acc2);
    acc3 = mfmaH(a, *(const short8*)(smem + (48 + lr) * 1024 + (kb ^ ((lr & 7) << 4))), acc3);
  }
  f32x4 accs[4] = {acc0, acc1, acc2, acc3};
#pragma unroll
  for (int nt = 0; nt < 4; ++nt) {
    int col = nt * 16 + lr;
    if (col < FF) {
      float bb = out_b[col];
#pragma unroll
      for (int e = 0; e < 4; ++e) {
        int row = r0 + lq * 4 + e;
        out[row * FF + col] = accs[nt][e] + bb;
      }
    }
  }
}

extern "C" void kernel_launch(void* const* d_in, const int* in_sizes, int n_in,
                              void* d_out, int out_size, void* d_ws, size_t ws_size,
                              hipStream_t stream) {
  const float* x = (const float*)d_in[0];
  const float* ew_ih0 = (const float*)d_in[1];
  const float* ew_hh0 = (const float*)d_in[2];
  const float* eb_ih0 = (const float*)d_in[3];
  const float* eb_hh0 = (const float*)d_in[4];
  const float* ew_ih1 = (const float*)d_in[5];
  const float* ew_hh1 = (const float*)d_in[6];
  const float* eb_ih1 = (const float*)d_in[7];
  const float* eb_hh1 = (const float*)d_in[8];
  const float* dw_ih0 = (const float*)d_in[9];
  const float* dw_hh0 = (const float*)d_in[10];
  const float* db_ih0 = (const float*)d_in[11];
  const float* db_hh0 = (const float*)d_in[12];
  const float* dw_ih1 = (const float*)d_in[13];
  const float* dw_hh1 = (const float*)d_in[14];
  const float* db_ih1 = (const float*)d_in[15];
  const float* db_hh1 = (const float*)d_in[16];
  const float* out_w = (const float*)d_in[17];
  const float* out_b = (const float*)d_in[18];

  char* ws = (char*)d_ws;
  int* cnt = (int*)(ws + OFF_CNT);
  unsigned short* hb = (unsigned short*)(ws + OFF_H);
  unsigned short* xhi = (unsigned short*)(ws + OFF_XHI);
  unsigned short* xlo = (unsigned short*)(ws + OFF_XLO);
  unsigned short* d1 = (unsigned short*)(ws + OFF_D1);

  (void)hipFuncSetAttribute((const void*)lstm_kernel, hipFuncAttributeMaxDynamicSharedMemorySize, 154944);
  (void)hipFuncSetAttribute((const void*)outproj_kernel, hipFuncAttributeMaxDynamicSharedMemorySize, 65536);

  init_kernel<<<1024, 256, 0, stream>>>(x, xhi, xlo, hb, cnt);
  lstm_kernel<<<256, 256, 154944, stream>>>(ew_ih0, ew_hh0, eb_ih0, eb_hh0,
                                            ew_ih1, ew_hh1, eb_ih1, eb_hh1,
                                            dw_ih0, dw_hh0, db_ih0, db_hh0,
                                            dw_ih1, dw_hh1, db_ih1, db_hh1,
                                            hb, xhi, xlo, d1, cnt);
  outproj_kernel<<<512, 256, 65536, stream>>>(d1, out_w, out_b, (float*)d_out);
}

// Round 9
// 13431.448 us; speedup vs baseline: 2.9299x; 2.7458x over previous
//
#include <hip/hip_runtime.h>
#include <hip/hip_bf16.h>

typedef short short8 __attribute__((ext_vector_type(8)));
typedef float f32x4 __attribute__((ext_vector_type(4)));
typedef unsigned u32;
typedef u32 u32x4 __attribute__((ext_vector_type(4)));
typedef _Float16 f16;

#define TT 512
#define BB 64
#define FF 51
#define HH 512
#define RNG 8   // h ring slots (power of 2, divides TT)

// workspace layout (bytes)
#define OFF_CNT  0          // counters: 2 groups * 256 ints (8 spread sub-counters / group)
#define OFF_RING 4096       // h rings: [group][layer][RNG][32][512] u32 (fp16 hi | lo<<16) = 2MB
#define OFF_XHI  2101248    // x hi fp16 padded [64][512][64] = 4MB
#define OFF_XLO  6295552    // x lo fp16 = 4MB
#define OFF_D1   10489856   // dec layer1 ys [64][512][512] fp16 = 32MB  (end 44,044,288)

__device__ __forceinline__ unsigned short h2u(f16 h) { return __builtin_bit_cast(unsigned short, h); }
__device__ __forceinline__ float sigm(float x) { return 1.f / (1.f + __expf(-x)); }
__device__ __forceinline__ float tanh_(float x) { return 1.f - 2.f / (__expf(2.f * x) + 1.f); }

__device__ __forceinline__ f32x4 mfmaH(short8 a, short8 b, f32x4 c) {
  asm("v_mfma_f32_16x16x32_f16 %0, %1, %2, %0" : "+v"(c) : "v"(a), "v"(b));
  return c;
}

// h publish: agent-scope atomic swap WITH RETURN (sc0). Return data arriving means the
// op executed at the coherence point; vmcnt retires only then, so the wave's
// __syncthreads() drain orders it before the (relaxed) barrier add.
__device__ __forceinline__ void st_h_swap(u32* p, u32 v) {
  u32 old;
  asm volatile("global_atomic_swap %0, %1, %2, off sc0"
               : "=&v"(old) : "v"(p), "v"(v) : "memory");
  (void)old;
}

__global__ void init_kernel(const float* __restrict__ x, unsigned short* __restrict__ xhi,
                            unsigned short* __restrict__ xlo, u32* __restrict__ ring,
                            int* __restrict__ cnt) {
  int tid = blockIdx.x * 256 + threadIdx.x;
  if (tid < 1024) cnt[tid] = 0;
  for (int i = tid; i < 2 * 2 * RNG * 16384; i += gridDim.x * 256) ring[i] = 0;
  for (int i = tid; i < BB * TT * 64; i += gridDim.x * 256) {
    int f = i & 63;
    int bt = i >> 6;
    float v = (f < FF) ? x[bt * FF + f] : 0.f;
    f16 hi = (f16)v;
    f16 lo = (f16)(v - (float)hi);
    xhi[i] = h2u(hi);
    xlo[i] = h2u(lo);
  }
}

__global__ __launch_bounds__(256, 1)
void lstm_kernel(const float* __restrict__ wih0e, const float* __restrict__ whh0e,
                 const float* __restrict__ bih0e, const float* __restrict__ bhh0e,
                 const float* __restrict__ wih1e, const float* __restrict__ whh1e,
                 const float* __restrict__ bih1e, const float* __restrict__ bhh1e,
                 const float* __restrict__ wih0d, const float* __restrict__ whh0d,
                 const float* __restrict__ bih0d, const float* __restrict__ bhh0d,
                 const float* __restrict__ wih1d, const float* __restrict__ whh1d,
                 const float* __restrict__ bih1d, const float* __restrict__ bhh1d,
                 u32* ring, const unsigned short* xhi, const unsigned short* xlo,
                 unsigned short* d1, int* cnt) {
  extern __shared__ char smem[];
  // W hi: [m][16][512] fp16 swizzled at m*16384 ; W lo at 49152+m*16384 (m: 0=hh0,1=ih1,2=hh1)
  char* wXhi = smem + 98304;               // [16][64] fp16
  char* wXlo = smem + 100352;
  float* bias = (float*)(smem + 102400);   // [2][16]
  float* gbuf = (float*)(smem + 102592);   // [18][16][17] fp32
  char* sh0hi = smem + 122176;             // [32][128] fp16 swizzled (K-chunk staging)
  char* sh0lo = smem + 130368;
  char* sh1hi = smem + 138560;
  char* sh1lo = smem + 146752;             // ends 154944

  const int tid = threadIdx.x;
  const int bid = blockIdx.x;
  const int group = bid & 1;     // 2 groups of 128 blocks
  const int slot = bid >> 1;     // 0..127 : owns 4 H-columns
  const int hc0 = slot * 4;
  const int wave = tid >> 6;
  const int lane = tid & 63;
  const int lr = lane & 15;      // fragment row/col index
  const int lq = lane >> 4;      // k-quarter
  const int bbase = group * 32;  // 32 chains per group

  u32* ring0 = ring + (group * 2 + 0) * RNG * 16384;   // h0 ring: [RNG][32][512] u32
  u32* ring1 = ring + (group * 2 + 1) * RNG * 16384;   // h1 ring
  int* mycnt = cnt + group * 256;                       // 8 sub-counters at stride 32 ints

  // elementwise ownership (persistent): thread -> (layer, chain, hcol); c in register
  const int eL = tid >> 7;
  const int eCi = (tid >> 2) & 31;
  const int eHc = tid & 3;
  float creg = 0.f;

  for (int phase = 0; phase < 2; ++phase) {
    const float* Wih0 = phase ? wih0d : wih0e;
    const float* Whh0 = phase ? whh0d : whh0e;
    const float* Wih1 = phase ? wih1d : wih1e;
    const float* Whh1 = phase ? whh1d : whh1e;
    // ---- load weight slices as fp16 hi+lo, swizzled ----
    for (int m = 0; m < 3; ++m) {
      const float* W = (m == 0) ? Whh0 : ((m == 1) ? Wih1 : Whh1);
      char* dHi = smem + m * 16384;
      char* dLo = smem + 49152 + m * 16384;
#pragma unroll
      for (int it = 0; it < 4; ++it) {
        int task = tid + it * 256;       // 0..1023
        int c8 = task & 63;              // 8-float chunk
        int r = task >> 6;               // local row 0..15 : gate r>>2, col hc0+(r&3)
        int grow = (r >> 2) * HH + hc0 + (r & 3);
        const float* src = W + grow * HH + c8 * 8;
        alignas(16) unsigned short thi[8], tlo[8];
#pragma unroll
        for (int e = 0; e < 8; ++e) {
          float v = src[e];
          f16 h = (f16)v;
          thi[e] = h2u(h);
          tlo[e] = h2u((f16)(v - (float)h));
        }
        int off = r * 1024 + ((c8 * 16) ^ ((r & 7) << 4));
        *(short8*)(dHi + off) = *(const short8*)thi;
        *(short8*)(dLo + off) = *(const short8*)tlo;
      }
    }
    if (tid < 128) {  // w_ih0 slice [16][64] hi+lo (features 51 padded)
      int c8 = tid & 7, r = tid >> 3;
      int grow = (r >> 2) * HH + hc0 + (r & 3);
      const float* src = Wih0 + grow * FF;
      alignas(16) unsigned short thi[8], tlo[8];
#pragma unroll
      for (int e = 0; e < 8; ++e) {
        int f = c8 * 8 + e;
        float v = (f < FF) ? src[f] : 0.f;
        f16 h = (f16)v;
        thi[e] = h2u(h);
        tlo[e] = h2u((f16)(v - (float)h));
      }
      int off = r * 128 + ((c8 * 16) ^ ((r & 7) << 4));
      *(short8*)(wXhi + off) = *(const short8*)thi;
      *(short8*)(wXlo + off) = *(const short8*)tlo;
    }
    if (tid < 32) {
      int L = tid >> 4, r = tid & 15;
      int grow = (r >> 2) * HH + hc0 + (r & 3);
      const float* bi = L ? (phase ? bih1d : bih1e) : (phase ? bih0d : bih0e);
      const float* bh = L ? (phase ? bhh1d : bhh1e) : (phase ? bhh0d : bhh0e);
      bias[L * 16 + r] = bi[grow] + bh[grow];
    }
    __syncthreads();

    // iteration k: layer0 does step k (k<TT); layer1 does step k-1 (k>=1)
    for (int k = 0; k <= TT; ++k) {
      // Periodic acquire: every RNG steps, every thread invalidates stale clean
      // L1/L2 lines before any ring slot address is re-read this epoch.
      if ((k & (RNG - 1)) == 0) __threadfence();

      const bool act0 = (k < TT), act1 = (k >= 1);
      // ring slot pointers (TT % RNG == 0 makes phase transitions seamless)
      const u32* s0G = ring0 + ((k + RNG - 1) & (RNG - 1)) * 16384;   // h0[k-1]
      const u32* s1G = ring1 + ((k + 2 * RNG - 2) & (RNG - 1)) * 16384; // h1[k-2]
      u32* w0G = ring0 + (k & (RNG - 1)) * 16384;                     // h0[k]
      u32* w1G = ring1 + ((k + RNG - 1) & (RNG - 1)) * 16384;         // h1[k-1]

      f32x4 acc[5];
#pragma unroll
      for (int i = 0; i < 5; ++i) acc[i] = (f32x4){0.f, 0.f, 0.f, 0.f};

      // x contribution (layer0 jobs j<6), A straight from global
      int xrow = phase ? (k == 0 ? TT - 1 : k - 1) : k;
#pragma unroll
      for (int i = 0; i < 5; ++i) {
        int j = wave + 4 * i;
        if (j < 6 && act0) {
          int t = j >> 1, mt = j & 1;
          const unsigned short* xa = (t == 2 ? xlo : xhi) +
              ((bbase + mt * 16 + lr) * TT + xrow) * 64 + lq * 8;
          const char* xb = (t == 1) ? wXlo : wXhi;
#pragma unroll
          for (int kk = 0; kk < 2; ++kk) {
            short8 a = *(const short8*)(xa + kk * 32);
            short8 b = *(const short8*)(xb + lr * 128 + ((kk * 64 + lq * 16) ^ ((lr & 7) << 4)));
            acc[i] = mfmaH(a, b, acc[i]);
          }
        }
      }

      // K-chunked staging + MFMA jobs. 18 jobs: [0,6)=hh0, [6,12)=ih1, [12,18)=hh1;
      // within sextet: jj=t*2+mt, t: 0=hi*Whi 1=hi*Wlo 2=lo*Whi
      for (int c = 0; c < 4; ++c) {
#pragma unroll
        for (int i2 = 0; i2 < 2; ++i2) {
          int task = tid + i2 * 256;          // 0..511
          int chain = task >> 4, k8 = task & 15;
          int srcOff = chain * 512 + c * 128 + k8 * 8;
          int dst = chain * 256 + ((k8 * 16) ^ ((chain & 7) << 4));
          u32x4 p0a = *(const u32x4*)(s0G + srcOff);
          u32x4 p0b = *(const u32x4*)(s0G + srcOff + 4);
          u32x4 p1a = *(const u32x4*)(s1G + srcOff);
          u32x4 p1b = *(const u32x4*)(s1G + srcOff + 4);
          alignas(16) unsigned short t0h[8], t0l[8], t1h[8], t1l[8];
#pragma unroll
          for (int e = 0; e < 4; ++e) {
            t0h[e]     = (unsigned short)(p0a[e] & 0xffffu); t0l[e]     = (unsigned short)(p0a[e] >> 16);
            t0h[4 + e] = (unsigned short)(p0b[e] & 0xffffu); t0l[4 + e] = (unsigned short)(p0b[e] >> 16);
            t1h[e]     = (unsigned short)(p1a[e] & 0xffffu); t1l[e]     = (unsigned short)(p1a[e] >> 16);
            t1h[4 + e] = (unsigned short)(p1b[e] & 0xffffu); t1l[4 + e] = (unsigned short)(p1b[e] >> 16);
          }
          *(short8*)(sh0hi + dst) = *(const short8*)t0h;
          *(short8*)(sh0lo + dst) = *(const short8*)t0l;
          *(short8*)(sh1hi + dst) = *(const short8*)t1h;
          *(short8*)(sh1lo + dst) = *(const short8*)t1l;
        }
        __syncthreads();
#pragma unroll
        for (int i = 0; i < 5; ++i) {
          int j = wave + 4 * i;
          if (j < 18) {
            bool act = (j < 6) ? act0 : act1;
            if (act) {
              int jj = (j < 6) ? j : ((j < 12) ? j - 6 : j - 12);
              int t = jj >> 1, mt = jj & 1;
              const char* A = (j < 12) ? (t == 2 ? sh0lo : sh0hi) : (t == 2 ? sh1lo : sh1hi);
              int m = (j < 6) ? 0 : ((j < 12) ? 1 : 2);
              const char* Bp = (t == 1) ? (smem + 49152 + m * 16384) : (smem + m * 16384);
              int arow = mt * 16 + lr;
              const char* Abase = A + arow * 256;
              int aswz = (arow & 7) << 4;
              const char* Bbase = Bp + lr * 1024;
              int bswz = (lr & 7) << 4;
#pragma unroll
              for (int kk = 0; kk < 4; ++kk) {
                short8 a = *(const short8*)(Abase + ((kk * 64 + lq * 16) ^ aswz));
                short8 b = *(const short8*)(Bbase + ((c * 256 + kk * 64 + lq * 16) ^ bswz));
                acc[i] = mfmaH(a, b, acc[i]);
              }
            }
          }
        }
        __syncthreads();
      }

      // publish fp32 partials: gbuf[j][chain(=lq*4+e)][row(=lr)]
#pragma unroll
      for (int i = 0; i < 5; ++i) {
        int j = wave + 4 * i;
        if (j < 18) {
#pragma unroll
          for (int e = 0; e < 4; ++e)
            gbuf[j * 272 + (lq * 4 + e) * 17 + lr] = acc[i][e];
        }
      }
      __syncthreads();

      // elementwise cell update: 1 (layer,chain,hcol) per thread.
      // h -> ring slot via atomic swap w/ return (at-LLC publish, no wbl2 needed).
      {
        bool act = eL ? act1 : act0;
        if (act) {
          int s = eL ? (k - 1) : k;
          int mt = eCi >> 4, cl = eCi & 15;
          float g[4];
#pragma unroll
          for (int q = 0; q < 4; ++q) {
            int ro = q * 4 + eHc;
            float v = bias[eL * 16 + ro];
            if (eL == 0) {
#pragma unroll
              for (int t = 0; t < 3; ++t) v += gbuf[(t * 2 + mt) * 272 + cl * 17 + ro];
            } else {
#pragma unroll
              for (int u = 0; u < 6; ++u) v += gbuf[(6 + u * 2 + mt) * 272 + cl * 17 + ro];
            }
            g[q] = v;
          }
          creg = sigm(g[1]) * creg + sigm(g[0]) * tanh_(g[2]);
          float h = sigm(g[3]) * tanh_(creg);
          f16 hhv = (f16)h;
          f16 hlv = (f16)(h - (float)hhv);
          u32 packed = (u32)h2u(hhv) | ((u32)h2u(hlv) << 16);
          u32* dst = (eL ? w1G : w0G) + eCi * 512 + hc0 + eHc;
          st_h_swap(dst, packed);
          if (eL && phase) d1[((bbase + eCi) * TT + s) * HH + hc0 + eHc] = h2u(hhv);
        }
      }
      __syncthreads();  // per-wave vmcnt drain: swap returns arrived -> data at LLC

      // group barrier: relaxed add on spread sub-counters (no wbl2), relaxed spin.
      __builtin_amdgcn_sched_barrier(0);
      if (tid == 0) {
        __hip_atomic_fetch_add(mycnt + (slot & 7) * 32, 1, __ATOMIC_RELAXED, __HIP_MEMORY_SCOPE_AGENT);
        int target = 128 * (phase * (TT + 1) + k + 1);
        long guard = 0;
        for (;;) {
          int sum = 0;
#pragma unroll
          for (int jj = 0; jj < 8; ++jj)
            sum += __hip_atomic_load(mycnt + jj * 32, __ATOMIC_RELAXED, __HIP_MEMORY_SCOPE_AGENT);
          if (sum >= target) break;
          if (++guard > (1L << 26)) break;   // anti-deadlock bail (turns hang into wrong-answer)
        }
      }
      __syncthreads();
    }
  }
}

__global__ __launch_bounds__(256, 1)
void outproj_kernel(const unsigned short* __restrict__ d1, const float* __restrict__ out_w,
                    const float* __restrict__ out_b, float* __restrict__ out) {
  extern __shared__ char smem[];
  const int tid = threadIdx.x;
#pragma unroll
  for (int i = 0; i < 16; ++i) {  // out_w [51][512] -> LDS [64][512] fp16 swizzled
    int task = tid + i * 256;
    int c8 = task & 63;
    int r = task >> 6;
    alignas(16) unsigned short tmp[8];
    if (r < FF) {
      const float* src = out_w + r * HH + c8 * 8;
#pragma unroll
      for (int e = 0; e < 8; ++e) tmp[e] = h2u((f16)src[e]);
    } else {
#pragma unroll
      for (int e = 0; e < 8; ++e) tmp[e] = 0;
    }
    *(short8*)(smem + r * 1024 + ((c8 * 16) ^ ((r & 7) << 4))) = *(const short8*)tmp;
  }
  __syncthreads();
  const int wave = tid >> 6, lane = tid & 63;
  const int lr = lane & 15, lq = lane >> 4;
  const int r0 = blockIdx.x * 64 + wave * 16;   // row in [B*T, H] view of d1
  f32x4 acc0 = {0.f, 0.f, 0.f, 0.f}, acc1 = acc0, acc2 = acc0, acc3 = acc0;
  const unsigned short* ap = d1 + (r0 + lr) * HH + lq * 8;
#pragma unroll
  for (int kk = 0; kk < 16; ++kk) {
    short8 a = *(const short8*)(ap + kk * 32);
    int kb = kk * 64 + lq * 16;
    acc0 = mfmaH(a, *(const short8*)(smem + (0 + lr) * 1024 + (kb ^ ((lr & 7) << 4))), acc0);
    acc1 = mfmaH(a, *(const short8*)(smem + (16 + lr) * 1024 + (kb ^ ((lr & 7) << 4))), acc1);
    acc2 = mfmaH(a, *(const short8*)(smem + (32 + lr) * 1024 + (kb ^ ((lr & 7) << 4))), acc2);
    acc3 = mfmaH(a, *(const short8*)(smem + (48 + lr) * 1024 + (kb ^ ((lr & 7) << 4))), acc3);
  }
  f32x4 accs[4] = {acc0, acc1, acc2, acc3};
#pragma unroll
  for (int nt = 0; nt < 4; ++nt) {
    int col = nt * 16 + lr;
    if (col < FF) {
      float bb = out_b[col];
#pragma unroll
      for (int e = 0; e < 4; ++e) {
        int row = r0 + lq * 4 + e;
        out[row * FF + col] = accs[nt][e] + bb;
      }
    }
  }
}

extern "C" void kernel_launch(void* const* d_in, const int* in_sizes, int n_in,
                              void* d_out, int out_size, void* d_ws, size_t ws_size,
                              hipStream_t stream) {
  const float* x = (const float*)d_in[0];
  const float* ew_ih0 = (const float*)d_in[1];
  const float* ew_hh0 = (const float*)d_in[2];
  const float* eb_ih0 = (const float*)d_in[3];
  const float* eb_hh0 = (const float*)d_in[4];
  const float* ew_ih1 = (const float*)d_in[5];
  const float* ew_hh1 = (const float*)d_in[6];
  const float* eb_ih1 = (const float*)d_in[7];
  const float* eb_hh1 = (const float*)d_in[8];
  const float* dw_ih0 = (const float*)d_in[9];
  const float* dw_hh0 = (const float*)d_in[10];
  const float* db_ih0 = (const float*)d_in[11];
  const float* db_hh0 = (const float*)d_in[12];
  const float* dw_ih1 = (const float*)d_in[13];
  const float* dw_hh1 = (const float*)d_in[14];
  const float* db_ih1 = (const float*)d_in[15];
  const float* db_hh1 = (const float*)d_in[16];
  const float* out_w = (const float*)d_in[17];
  const float* out_b = (const float*)d_in[18];

  char* ws = (char*)d_ws;
  int* cnt = (int*)(ws + OFF_CNT);
  u32* ring = (u32*)(ws + OFF_RING);
  unsigned short* xhi = (unsigned short*)(ws + OFF_XHI);
  unsigned short* xlo = (unsigned short*)(ws + OFF_XLO);
  unsigned short* d1 = (unsigned short*)(ws + OFF_D1);

  (void)hipFuncSetAttribute((const void*)lstm_kernel, hipFuncAttributeMaxDynamicSharedMemorySize, 154944);
  (void)hipFuncSetAttribute((const void*)outproj_kernel, hipFuncAttributeMaxDynamicSharedMemorySize, 65536);

  init_kernel<<<1024, 256, 0, stream>>>(x, xhi, xlo, ring, cnt);
  lstm_kernel<<<256, 256, 154944, stream>>>(ew_ih0, ew_hh0, eb_ih0, eb_hh0,
                                            ew_ih1, ew_hh1, eb_ih1, eb_hh1,
                                            dw_ih0, dw_hh0, db_ih0, db_hh0,
                                            dw_ih1, dw_hh1, db_ih1, db_hh1,
                                            ring, xhi, xlo, d1, cnt);
  outproj_kernel<<<512, 256, 65536, stream>>>(d1, out_w, out_b, (float*)d_out);
}

// Round 13
// 12694.601 us; speedup vs baseline: 3.1000x; 1.0580x over previous
//
#include <hip/hip_runtime.h>
#include <hip/hip_bf16.h>

typedef short short8 __attribute__((ext_vector_type(8)));
typedef float f32x4 __attribute__((ext_vector_type(4)));
typedef unsigned u32;
typedef u32 u32x4 __attribute__((ext_vector_type(4)));
typedef _Float16 f16;

#define TT 512
#define BB 64
#define FF 51
#define HH 512
#define RNG 8   // h ring slots (power of 2, divides TT)

// workspace layout (bytes) — identical to R9
#define OFF_CNT  0          // counters: 2 groups * 256 ints (8 spread sub-counters / group)
#define OFF_RING 4096       // h rings: [group][layer][RNG][32][512] u32 (fp16 hi | lo<<16) = 2MB
#define OFF_XHI  2101248    // x hi fp16 padded [64][512][64] = 4MB
#define OFF_XLO  6295552    // x lo fp16 = 4MB
#define OFF_D1   10489856   // dec layer1 ys [64][512][512] fp16 = 32MB  (end 44,044,288)

__device__ __forceinline__ unsigned short h2u(f16 h) { return __builtin_bit_cast(unsigned short, h); }
__device__ __forceinline__ float sigm(float x) { return 1.f / (1.f + __expf(-x)); }
__device__ __forceinline__ float tanh_(float x) { return 1.f - 2.f / (__expf(2.f * x) + 1.f); }

__device__ __forceinline__ f32x4 mfmaH(short8 a, short8 b, f32x4 c) {
  asm("v_mfma_f32_16x16x32_f16 %0, %1, %2, %0" : "+v"(c) : "v"(a), "v"(b));
  return c;
}

// h publish: agent-scope atomic swap WITH RETURN (sc0), R9-proven.
__device__ __forceinline__ void st_h_swap(u32* p, u32 v) {
  u32 old;
  asm volatile("global_atomic_swap %0, %1, %2, off sc0"
               : "=&v"(old) : "v"(p), "v"(v) : "memory");
  (void)old;
}

__global__ void init_kernel(const float* __restrict__ x, unsigned short* __restrict__ xhi,
                            unsigned short* __restrict__ xlo, u32* __restrict__ ring,
                            int* __restrict__ cnt) {
  int tid = blockIdx.x * 256 + threadIdx.x;
  if (tid < 1024) cnt[tid] = 0;
  for (int i = tid; i < 2 * 2 * RNG * 16384; i += gridDim.x * 256) ring[i] = 0;
  for (int i = tid; i < BB * TT * 64; i += gridDim.x * 256) {
    int f = i & 63;
    int bt = i >> 6;
    float v = (f < FF) ? x[bt * FF + f] : 0.f;
    f16 hi = (f16)v;
    f16 lo = (f16)(v - (float)hi);
    xhi[i] = h2u(hi);
    xlo[i] = h2u(lo);
  }
}

__global__ __launch_bounds__(512, 1)
void lstm_kernel(const float* __restrict__ wih0e, const float* __restrict__ whh0e,
                 const float* __restrict__ bih0e, const float* __restrict__ bhh0e,
                 const float* __restrict__ wih1e, const float* __restrict__ whh1e,
                 const float* __restrict__ bih1e, const float* __restrict__ bhh1e,
                 const float* __restrict__ wih0d, const float* __restrict__ whh0d,
                 const float* __restrict__ bih0d, const float* __restrict__ bhh0d,
                 const float* __restrict__ wih1d, const float* __restrict__ whh1d,
                 const float* __restrict__ bih1d, const float* __restrict__ bhh1d,
                 u32* ring, const unsigned short* xhi, const unsigned short* xlo,
                 unsigned short* d1, int* cnt) {
  extern __shared__ char smem[];
  // W hi: [m][16][512] fp16 swizzled at m*16384 ; W lo at 49152+m*16384 (m: 0=hh0,1=ih1,2=hh1)
  char* wXhi = smem + 98304;               // [16][64] fp16
  char* wXlo = smem + 100352;
  float* bias = (float*)(smem + 102400);   // [2][16]
  float* gbuf = (float*)(smem + 102592);   // [18][16][17] fp32
  char* sh0hi = smem + 122176;             // [32][128] fp16 swizzled (K-chunk staging)
  char* sh0lo = smem + 130368;
  char* sh1hi = smem + 138560;
  char* sh1lo = smem + 146752;             // ends 154944

  const int tid = threadIdx.x;             // 0..511 (8 waves)
  const int bid = blockIdx.x;
  const int group = bid & 1;     // 2 groups of 128 blocks
  const int slot = bid >> 1;     // 0..127 : owns 4 H-columns
  const int hc0 = slot * 4;
  const int wave = tid >> 6;     // 0..7
  const int lane = tid & 63;
  const int lr = lane & 15;      // fragment row/col index
  const int lq = lane >> 4;      // k-quarter
  const int bbase = group * 32;  // 32 chains per group

  u32* ring0 = ring + (group * 2 + 0) * RNG * 16384;   // h0 ring: [RNG][32][512] u32
  u32* ring1 = ring + (group * 2 + 1) * RNG * 16384;   // h1 ring
  int* mycnt = cnt + group * 256;                       // 8 sub-counters at stride 32 ints

  // elementwise ownership (tid<256): thread -> (layer, chain, hcol); c in register
  const int eL = (tid >> 7) & 1;
  const int eCi = (tid >> 2) & 31;
  const int eHc = tid & 3;
  float creg = 0.f;

  for (int phase = 0; phase < 2; ++phase) {
    const float* Wih0 = phase ? wih0d : wih0e;
    const float* Whh0 = phase ? whh0d : whh0e;
    const float* Wih1 = phase ? wih1d : wih1e;
    const float* Whh1 = phase ? whh1d : whh1e;
    // ---- load weight slices as fp16 hi+lo, swizzled ----
    for (int m = 0; m < 3; ++m) {
      const float* W = (m == 0) ? Whh0 : ((m == 1) ? Wih1 : Whh1);
      char* dHi = smem + m * 16384;
      char* dLo = smem + 49152 + m * 16384;
#pragma unroll
      for (int it = 0; it < 2; ++it) {
        int task = tid + it * 512;       // 0..1023
        int c8 = task & 63;              // 8-float chunk
        int r = task >> 6;               // local row 0..15 : gate r>>2, col hc0+(r&3)
        int grow = (r >> 2) * HH + hc0 + (r & 3);
        const float* src = W + grow * HH + c8 * 8;
        alignas(16) unsigned short thi[8], tlo[8];
#pragma unroll
        for (int e = 0; e < 8; ++e) {
          float v = src[e];
          f16 h = (f16)v;
          thi[e] = h2u(h);
          tlo[e] = h2u((f16)(v - (float)h));
        }
        int off = r * 1024 + ((c8 * 16) ^ ((r & 7) << 4));
        *(short8*)(dHi + off) = *(const short8*)thi;
        *(short8*)(dLo + off) = *(const short8*)tlo;
      }
    }
    if (tid < 128) {  // w_ih0 slice [16][64] hi+lo (features 51 padded)
      int c8 = tid & 7, r = tid >> 3;
      int grow = (r >> 2) * HH + hc0 + (r & 3);
      const float* src = Wih0 + grow * FF;
      alignas(16) unsigned short thi[8], tlo[8];
#pragma unroll
      for (int e = 0; e < 8; ++e) {
        int f = c8 * 8 + e;
        float v = (f < FF) ? src[f] : 0.f;
        f16 h = (f16)v;
        thi[e] = h2u(h);
        tlo[e] = h2u((f16)(v - (float)h));
      }
      int off = r * 128 + ((c8 * 16) ^ ((r & 7) << 4));
      *(short8*)(wXhi + off) = *(const short8*)thi;
      *(short8*)(wXlo + off) = *(const short8*)tlo;
    }
    if (tid < 32) {
      int L = tid >> 4, r = tid & 15;
      int grow = (r >> 2) * HH + hc0 + (r & 3);
      const float* bi = L ? (phase ? bih1d : bih1e) : (phase ? bih0d : bih0e);
      const float* bh = L ? (phase ? bhh1d : bhh1e) : (phase ? bhh0d : bhh0e);
      bias[L * 16 + r] = bi[grow] + bh[grow];
    }
    __syncthreads();

    // iteration k: layer0 does step k (k<TT); layer1 does step k-1 (k>=1)
    for (int k = 0; k <= TT; ++k) {
      // Periodic acquire (R9-proven): every RNG steps, every thread invalidates
      // stale clean L1/L2 lines before any ring slot address is re-read.
      if ((k & (RNG - 1)) == 0) __threadfence();

      const bool act0 = (k < TT), act1 = (k >= 1);
      // ring slot pointers (TT % RNG == 0 makes phase transitions seamless)
      const u32* s0G = ring0 + ((k + RNG - 1) & (RNG - 1)) * 16384;     // h0[k-1]
      const u32* s1G = ring1 + ((k + 2 * RNG - 2) & (RNG - 1)) * 16384; // h1[k-2]
      u32* w0G = ring0 + (k & (RNG - 1)) * 16384;                       // h0[k]
      u32* w1G = ring1 + ((k + RNG - 1) & (RNG - 1)) * 16384;           // h1[k-1]

      f32x4 acc[3];
#pragma unroll
      for (int i = 0; i < 3; ++i) acc[i] = (f32x4){0.f, 0.f, 0.f, 0.f};

      // x contribution (layer0 jobs j<6): one job per wave (waves 0..5).
      // Job j accumulates in acc[0] — same accumulator its hh0 h-job (i=0, j=wave)
      // adds to, exactly as in R9's shared-j accumulation.
      int xrow = phase ? (k == 0 ? TT - 1 : k - 1) : k;
      if (act0 && wave < 6) {
        int t = wave >> 1, mt = wave & 1;
        const unsigned short* xa = (t == 2 ? xlo : xhi) +
            ((bbase + mt * 16 + lr) * TT + xrow) * 64 + lq * 8;
        const char* xb = (t == 1) ? wXlo : wXhi;
#pragma unroll
        for (int kk = 0; kk < 2; ++kk) {
          short8 a = *(const short8*)(xa + kk * 32);
          short8 b = *(const short8*)(xb + lr * 128 + ((kk * 64 + lq * 16) ^ ((lr & 7) << 4)));
          acc[0] = mfmaH(a, b, acc[0]);
        }
      }

      // K-chunked staging + MFMA jobs — loads in the R9-proven position:
      // per-chunk, adjacent to the LDS write, after the x-section.
      // 18 jobs: [0,6)=hh0, [6,12)=ih1, [12,18)=hh1; within sextet jj=t*2+mt,
      // t: 0=hi*Whi 1=hi*Wlo 2=lo*Whi
      for (int c = 0; c < 4; ++c) {
        {
          int chain = tid >> 4, k8 = tid & 15;     // 512 tasks, one per thread
          int srcOff = chain * 512 + c * 128 + k8 * 8;
          int dst = chain * 256 + ((k8 * 16) ^ ((chain & 7) << 4));
          u32x4 p0a = *(const u32x4*)(s0G + srcOff);
          u32x4 p0b = *(const u32x4*)(s0G + srcOff + 4);
          u32x4 p1a = *(const u32x4*)(s1G + srcOff);
          u32x4 p1b = *(const u32x4*)(s1G + srcOff + 4);
          alignas(16) unsigned short t0h[8], t0l[8], t1h[8], t1l[8];
#pragma unroll
          for (int e = 0; e < 4; ++e) {
            t0h[e]     = (unsigned short)(p0a[e] & 0xffffu); t0l[e]     = (unsigned short)(p0a[e] >> 16);
            t0h[4 + e] = (unsigned short)(p0b[e] & 0xffffu); t0l[4 + e] = (unsigned short)(p0b[e] >> 16);
            t1h[e]     = (unsigned short)(p1a[e] & 0xffffu); t1l[e]     = (unsigned short)(p1a[e] >> 16);
            t1h[4 + e] = (unsigned short)(p1b[e] & 0xffffu); t1l[4 + e] = (unsigned short)(p1b[e] >> 16);
          }
          *(short8*)(sh0hi + dst) = *(const short8*)t0h;
          *(short8*)(sh0lo + dst) = *(const short8*)t0l;
          *(short8*)(sh1hi + dst) = *(const short8*)t1h;
          *(short8*)(sh1lo + dst) = *(const short8*)t1l;
        }
        __syncthreads();
#pragma unroll
        for (int i = 0; i < 3; ++i) {
          int j = wave + 8 * i;
          if (j < 18) {
            bool act = (j < 6) ? act0 : act1;
            if (act) {
              int jj = (j < 6) ? j : ((j < 12) ? j - 6 : j - 12);
              int t = jj >> 1, mt = jj & 1;
              const char* A = (j < 12) ? (t == 2 ? sh0lo : sh0hi) : (t == 2 ? sh1lo : sh1hi);
              int m = (j < 6) ? 0 : ((j < 12) ? 1 : 2);
              const char* Bp = (t == 1) ? (smem + 49152 + m * 16384) : (smem + m * 16384);
              int arow = mt * 16 + lr;
              const char* Abase = A + arow * 256;
              int aswz = (arow & 7) << 4;
              const char* Bbase = Bp + lr * 1024;
              int bswz = (lr & 7) << 4;
#pragma unroll
              for (int kk = 0; kk < 4; ++kk) {
                short8 a = *(const short8*)(Abase + ((kk * 64 + lq * 16) ^ aswz));
                short8 b = *(const short8*)(Bbase + ((c * 256 + kk * 64 + lq * 16) ^ bswz));
                acc[i] = mfmaH(a, b, acc[i]);
              }
            }
          }
        }
        __syncthreads();
      }

      // publish fp32 partials: gbuf[j][chain(=lq*4+e)][row(=lr)]
#pragma unroll
      for (int i = 0; i < 3; ++i) {
        int j = wave + 8 * i;
        if (j < 18) {
#pragma unroll
          for (int e = 0; e < 4; ++e)
            gbuf[j * 272 + (lq * 4 + e) * 17 + lr] = acc[i][e];
        }
      }
      __syncthreads();

      // elementwise cell update: tid<256 -> 1 (layer,chain,hcol) per thread.
      // h -> ring slot via atomic swap w/ return (at-LLC publish, R9-proven).
      if (tid < 256) {
        bool act = eL ? act1 : act0;
        if (act) {
          int s = eL ? (k - 1) : k;
          int mt = eCi >> 4, cl = eCi & 15;
          float g[4];
#pragma unroll
          for (int q = 0; q < 4; ++q) {
            int ro = q * 4 + eHc;
            float v = bias[eL * 16 + ro];
            if (eL == 0) {
#pragma unroll
              for (int t = 0; t < 3; ++t) v += gbuf[(t * 2 + mt) * 272 + cl * 17 + ro];
            } else {
#pragma unroll
              for (int u = 0; u < 6; ++u) v += gbuf[(6 + u * 2 + mt) * 272 + cl * 17 + ro];
            }
            g[q] = v;
          }
          creg = sigm(g[1]) * creg + sigm(g[0]) * tanh_(g[2]);
          float h = sigm(g[3]) * tanh_(creg);
          f16 hhv = (f16)h;
          f16 hlv = (f16)(h - (float)hhv);
          u32 packed = (u32)h2u(hhv) | ((u32)h2u(hlv) << 16);
          u32* dst = (eL ? w1G : w0G) + eCi * 512 + hc0 + eHc;
          st_h_swap(dst, packed);
          if (eL && phase) d1[((bbase + eCi) * TT + s) * HH + hc0 + eHc] = h2u(hhv);
        }
      }
      __syncthreads();  // per-wave vmcnt drain: swap returns arrived -> data at LLC

      // group barrier: relaxed add on spread sub-counters (no wbl2), relaxed spin.
      __builtin_amdgcn_sched_barrier(0);
      if (tid == 0) {
        __hip_atomic_fetch_add(mycnt + (slot & 7) * 32, 1, __ATOMIC_RELAXED, __HIP_MEMORY_SCOPE_AGENT);
        int target = 128 * (phase * (TT + 1) + k + 1);
        long guard = 0;
        for (;;) {
          int sum = 0;
#pragma unroll
          for (int jj = 0; jj < 8; ++jj)
            sum += __hip_atomic_load(mycnt + jj * 32, __ATOMIC_RELAXED, __HIP_MEMORY_SCOPE_AGENT);
          if (sum >= target) break;
          if (++guard > (1L << 26)) break;   // anti-deadlock bail (turns hang into wrong-answer)
        }
      }
      __syncthreads();
    }
  }
}

__global__ __launch_bounds__(256, 1)
void outproj_kernel(const unsigned short* __restrict__ d1, const float* __restrict__ out_w,
                    const float* __restrict__ out_b, float* __restrict__ out) {
  extern __shared__ char smem[];
  const int tid = threadIdx.x;
#pragma unroll
  for (int i = 0; i < 16; ++i) {  // out_w [51][512] -> LDS [64][512] fp16 swizzled
    int task = tid + i * 256;
    int c8 = task & 63;
    int r = task >> 6;
    alignas(16) unsigned short tmp[8];
    if (r < FF) {
      const float* src = out_w + r * HH + c8 * 8;
#pragma unroll
      for (int e = 0; e < 8; ++e) tmp[e] = h2u((f16)src[e]);
    } else {
#pragma unroll
      for (int e = 0; e < 8; ++e) tmp[e] = 0;
    }
    *(short8*)(smem + r * 1024 + ((c8 * 16) ^ ((r & 7) << 4))) = *(const short8*)tmp;
  }
  __syncthreads();
  const int wave = tid >> 6, lane = tid & 63;
  const int lr = lane & 15, lq = lane >> 4;
  const int r0 = blockIdx.x * 64 + wave * 16;   // row in [B*T, H] view of d1
  f32x4 acc0 = {0.f, 0.f, 0.f, 0.f}, acc1 = acc0, acc2 = acc0, acc3 = acc0;
  const unsigned short* ap = d1 + (r0 + lr) * HH + lq * 8;
#pragma unroll
  for (int kk = 0; kk < 16; ++kk) {
    short8 a = *(const short8*)(ap + kk * 32);
    int kb = kk * 64 + lq * 16;
    acc0 = mfmaH(a, *(const short8*)(smem + (0 + lr) * 1024 + (kb ^ ((lr & 7) << 4))), acc0);
    acc1 = mfmaH(a, *(const short8*)(smem + (16 + lr) * 1024 + (kb ^ ((lr & 7) << 4))), acc1);
    acc2 = mfmaH(a, *(const short8*)(smem + (32 + lr) * 1024 + (kb ^ ((lr & 7) << 4))), acc2);
    acc3 = mfmaH(a, *(const short8*)(smem + (48 + lr) * 1024 + (kb ^ ((lr & 7) << 4))), acc3);
  }
  f32x4 accs[4] = {acc0, acc1, acc2, acc3};
#pragma unroll
  for (int nt = 0; nt < 4; ++nt) {
    int col = nt * 16 + lr;
    if (col < FF) {
      float bb = out_b[col];
#pragma unroll
      for (int e = 0; e < 4; ++e) {
        int row = r0 + lq * 4 + e;
        out[row * FF + col] = accs[nt][e] + bb;
      }
    }
  }
}

extern "C" void kernel_launch(void* const* d_in, const int* in_sizes, int n_in,
                              void* d_out, int out_size, void* d_ws, size_t ws_size,
                              hipStream_t stream) {
  const float* x = (const float*)d_in[0];
  const float* ew_ih0 = (const float*)d_in[1];
  const float* ew_hh0 = (const float*)d_in[2];
  const float* eb_ih0 = (const float*)d_in[3];
  const float* eb_hh0 = (const float*)d_in[4];
  const float* ew_ih1 = (const float*)d_in[5];
  const float* ew_hh1 = (const float*)d_in[6];
  const float* eb_ih1 = (const float*)d_in[7];
  const float* eb_hh1 = (const float*)d_in[8];
  const float* dw_ih0 = (const float*)d_in[9];
  const float* dw_hh0 = (const float*)d_in[10];
  const float* db_ih0 = (const float*)d_in[11];
  const float* db_hh0 = (const float*)d_in[12];
  const float* dw_ih1 = (const float*)d_in[13];
  const float* dw_hh1 = (const float*)d_in[14];
  const float* db_ih1 = (const float*)d_in[15];
  const float* db_hh1 = (const float*)d_in[16];
  const float* out_w = (const float*)d_in[17];
  const float* out_b = (const float*)d_in[18];

  char* ws = (char*)d_ws;
  int* cnt = (int*)(ws + OFF_CNT);
  u32* ring = (u32*)(ws + OFF_RING);
  unsigned short* xhi = (unsigned short*)(ws + OFF_XHI);
  unsigned short* xlo = (unsigned short*)(ws + OFF_XLO);
  unsigned short* d1 = (unsigned short*)(ws + OFF_D1);

  (void)hipFuncSetAttribute((const void*)lstm_kernel, hipFuncAttributeMaxDynamicSharedMemorySize, 154944);
  (void)hipFuncSetAttribute((const void*)outproj_kernel, hipFuncAttributeMaxDynamicSharedMemorySize, 65536);

  init_kernel<<<1024, 256, 0, stream>>>(x, xhi, xlo, ring, cnt);
  lstm_kernel<<<256, 512, 154944, stream>>>(ew_ih0, ew_hh0, eb_ih0, eb_hh0,
                                            ew_ih1, ew_hh1, eb_ih1, eb_hh1,
                                            dw_ih0, dw_hh0, db_ih0, db_hh0,
                                            dw_ih1, dw_hh1, db_ih1, db_hh1,
                                            ring, xhi, xlo, d1, cnt);
  outproj_kernel<<<512, 256, 65536, stream>>>(d1, out_w, out_b, (float*)d_out);
}

// Round 16
// 12268.166 us; speedup vs baseline: 3.2078x; 1.0348x over previous
//
#include <hip/hip_runtime.h>
#include <hip/hip_bf16.h>

typedef short short8 __attribute__((ext_vector_type(8)));
typedef float f32x4 __attribute__((ext_vector_type(4)));
typedef unsigned u32;
typedef u32 u32x4 __attribute__((ext_vector_type(4)));
typedef _Float16 f16;

#define TT 512
#define BB 64
#define FF 51
#define HH 512
#define RNG 8   // h ring slots (power of 2, divides TT)

// workspace layout (bytes) — identical to R9/R13 (cnt region re-carved: 2 groups
// x 32 sub-counters at 64B stride = 4KB total, same region)
#define OFF_CNT  0
#define OFF_RING 4096       // h rings: [group][layer][RNG][32][512] u32 (fp16 hi | lo<<16) = 2MB
#define OFF_XHI  2101248    // x hi fp16 padded [64][512][64] = 4MB
#define OFF_XLO  6295552    // x lo fp16 = 4MB
#define OFF_D1   10489856   // dec layer1 ys [64][512][512] fp16 = 32MB  (end 44,044,288)

__device__ __forceinline__ unsigned short h2u(f16 h) { return __builtin_bit_cast(unsigned short, h); }
__device__ __forceinline__ float sigm(float x) { return 1.f / (1.f + __expf(-x)); }
__device__ __forceinline__ float tanh_(float x) { return 1.f - 2.f / (__expf(2.f * x) + 1.f); }

__device__ __forceinline__ f32x4 mfmaH(short8 a, short8 b, f32x4 c) {
  asm("v_mfma_f32_16x16x32_f16 %0, %1, %2, %0" : "+v"(c) : "v"(a), "v"(b));
  return c;
}

// h publish: agent-scope atomic swap WITH RETURN (sc0), R9-proven.
__device__ __forceinline__ void st_h_swap(u32* p, u32 v) {
  u32 old;
  asm volatile("global_atomic_swap %0, %1, %2, off sc0"
               : "=&v"(old) : "v"(p), "v"(v) : "memory");
  (void)old;
}

__global__ void init_kernel(const float* __restrict__ x, unsigned short* __restrict__ xhi,
                            unsigned short* __restrict__ xlo, u32* __restrict__ ring,
                            int* __restrict__ cnt) {
  int tid = blockIdx.x * 256 + threadIdx.x;
  if (tid < 1024) cnt[tid] = 0;
  for (int i = tid; i < 2 * 2 * RNG * 16384; i += gridDim.x * 256) ring[i] = 0;
  for (int i = tid; i < BB * TT * 64; i += gridDim.x * 256) {
    int f = i & 63;
    int bt = i >> 6;
    float v = (f < FF) ? x[bt * FF + f] : 0.f;
    f16 hi = (f16)v;
    f16 lo = (f16)(v - (float)hi);
    xhi[i] = h2u(hi);
    xlo[i] = h2u(lo);
  }
}

__global__ __launch_bounds__(512, 1)
void lstm_kernel(const float* __restrict__ wih0e, const float* __restrict__ whh0e,
                 const float* __restrict__ bih0e, const float* __restrict__ bhh0e,
                 const float* __restrict__ wih1e, const float* __restrict__ whh1e,
                 const float* __restrict__ bih1e, const float* __restrict__ bhh1e,
                 const float* __restrict__ wih0d, const float* __restrict__ whh0d,
                 const float* __restrict__ bih0d, const float* __restrict__ bhh0d,
                 const float* __restrict__ wih1d, const float* __restrict__ whh1d,
                 const float* __restrict__ bih1d, const float* __restrict__ bhh1d,
                 u32* ring, const unsigned short* xhi, const unsigned short* xlo,
                 unsigned short* d1, int* cnt) {
  extern __shared__ char smem[];
  // W hi: [m][16][512] fp16 swizzled at m*16384 ; W lo at 49152+m*16384 (m: 0=hh0,1=ih1,2=hh1)
  char* wXhi = smem + 98304;               // [16][64] fp16
  char* wXlo = smem + 100352;
  float* bias = (float*)(smem + 102400);   // [2][16]
  float* gbuf = (float*)(smem + 102592);   // [18][16][17] fp32
  char* sh0hi = smem + 122176;             // [32][128] fp16 swizzled (K-chunk staging)
  char* sh0lo = smem + 130368;
  char* sh1hi = smem + 138560;
  char* sh1lo = smem + 146752;             // ends 154944

  const int tid = threadIdx.x;             // 0..511 (8 waves)
  const int bid = blockIdx.x;
  const int group = bid & 1;     // 2 groups of 128 blocks
  const int slot = bid >> 1;     // 0..127 : owns 4 H-columns
  const int hc0 = slot * 4;
  const int wave = tid >> 6;     // 0..7
  const int lane = tid & 63;
  const int lr = lane & 15;      // fragment row/col index
  const int lq = lane >> 4;      // k-quarter
  const int bbase = group * 32;  // 32 chains per group

  u32* ring0 = ring + (group * 2 + 0) * RNG * 16384;   // h0 ring: [RNG][32][512] u32
  u32* ring1 = ring + (group * 2 + 1) * RNG * 16384;   // h1 ring
  int* mycnt = cnt + group * 512;          // 32 sub-counters at stride 16 ints (64B lines)

  // elementwise ownership (tid<256): thread -> (layer, chain, hcol); c in register
  const int eL = (tid >> 7) & 1;
  const int eCi = (tid >> 2) & 31;
  const int eHc = tid & 3;
  float creg = 0.f;

  for (int phase = 0; phase < 2; ++phase) {
    const float* Wih0 = phase ? wih0d : wih0e;
    const float* Whh0 = phase ? whh0d : whh0e;
    const float* Wih1 = phase ? wih1d : wih1e;
    const float* Whh1 = phase ? whh1d : whh1e;
    // ---- load weight slices as fp16 hi+lo, swizzled ----
    for (int m = 0; m < 3; ++m) {
      const float* W = (m == 0) ? Whh0 : ((m == 1) ? Wih1 : Whh1);
      char* dHi = smem + m * 16384;
      char* dLo = smem + 49152 + m * 16384;
#pragma unroll
      for (int it = 0; it < 2; ++it) {
        int task = tid + it * 512;       // 0..1023
        int c8 = task & 63;              // 8-float chunk
        int r = task >> 6;               // local row 0..15 : gate r>>2, col hc0+(r&3)
        int grow = (r >> 2) * HH + hc0 + (r & 3);
        const float* src = W + grow * HH + c8 * 8;
        alignas(16) unsigned short thi[8], tlo[8];
#pragma unroll
        for (int e = 0; e < 8; ++e) {
          float v = src[e];
          f16 h = (f16)v;
          thi[e] = h2u(h);
          tlo[e] = h2u((f16)(v - (float)h));
        }
        int off = r * 1024 + ((c8 * 16) ^ ((r & 7) << 4));
        *(short8*)(dHi + off) = *(const short8*)thi;
        *(short8*)(dLo + off) = *(const short8*)tlo;
      }
    }
    if (tid < 128) {  // w_ih0 slice [16][64] hi+lo (features 51 padded)
      int c8 = tid & 7, r = tid >> 3;
      int grow = (r >> 2) * HH + hc0 + (r & 3);
      const float* src = Wih0 + grow * FF;
      alignas(16) unsigned short thi[8], tlo[8];
#pragma unroll
      for (int e = 0; e < 8; ++e) {
        int f = c8 * 8 + e;
        float v = (f < FF) ? src[f] : 0.f;
        f16 h = (f16)v;
        thi[e] = h2u(h);
        tlo[e] = h2u((f16)(v - (float)h));
      }
      int off = r * 128 + ((c8 * 16) ^ ((r & 7) << 4));
      *(short8*)(wXhi + off) = *(const short8*)thi;
      *(short8*)(wXlo + off) = *(const short8*)tlo;
    }
    if (tid < 32) {
      int L = tid >> 4, r = tid & 15;
      int grow = (r >> 2) * HH + hc0 + (r & 3);
      const float* bi = L ? (phase ? bih1d : bih1e) : (phase ? bih0d : bih0e);
      const float* bh = L ? (phase ? bhh1d : bhh1e) : (phase ? bhh0d : bhh0e);
      bias[L * 16 + r] = bi[grow] + bh[grow];
    }
    __syncthreads();

    // iteration k: layer0 does step k (k<TT); layer1 does step k-1 (k>=1)
    for (int k = 0; k <= TT; ++k) {
      // Periodic acquire (R9-proven): every RNG steps, every thread invalidates
      // stale clean L1/L2 lines before any ring slot address is re-read.
      if ((k & (RNG - 1)) == 0) __threadfence();

      const bool act0 = (k < TT), act1 = (k >= 1);
      // ring slot pointers (TT % RNG == 0 makes phase transitions seamless)
      const u32* s0G = ring0 + ((k + RNG - 1) & (RNG - 1)) * 16384;     // h0[k-1]
      const u32* s1G = ring1 + ((k + 2 * RNG - 2) & (RNG - 1)) * 16384; // h1[k-2]
      u32* w0G = ring0 + (k & (RNG - 1)) * 16384;                       // h0[k]
      u32* w1G = ring1 + ((k + RNG - 1) & (RNG - 1)) * 16384;           // h1[k-1]

      f32x4 acc[3];
#pragma unroll
      for (int i = 0; i < 3; ++i) acc[i] = (f32x4){0.f, 0.f, 0.f, 0.f};

      // x contribution (layer0 jobs j<6): one job per wave (waves 0..5),
      // accumulating into acc[0] (same accumulator as its hh0 h-job j=wave).
      int xrow = phase ? (k == 0 ? TT - 1 : k - 1) : k;
      if (act0 && wave < 6) {
        int t = wave >> 1, mt = wave & 1;
        const unsigned short* xa = (t == 2 ? xlo : xhi) +
            ((bbase + mt * 16 + lr) * TT + xrow) * 64 + lq * 8;
        const char* xb = (t == 1) ? wXlo : wXhi;
#pragma unroll
        for (int kk = 0; kk < 2; ++kk) {
          short8 a = *(const short8*)(xa + kk * 32);
          short8 b = *(const short8*)(xb + lr * 128 + ((kk * 64 + lq * 16) ^ ((lr & 7) << 4)));
          acc[0] = mfmaH(a, b, acc[0]);
        }
      }

      // K-chunked staging + MFMA jobs — loads in the R9-proven position:
      // per-chunk, adjacent to the LDS write, after the x-section. Rolled loop
      // (no unroll) so the compiler cannot hoist later chunks' loads.
      // 18 jobs: [0,6)=hh0, [6,12)=ih1, [12,18)=hh1; within sextet jj=t*2+mt,
      // t: 0=hi*Whi 1=hi*Wlo 2=lo*Whi
      for (int c = 0; c < 4; ++c) {
        {
          int chain = tid >> 4, k8 = tid & 15;     // 512 tasks, one per thread
          int srcOff = chain * 512 + c * 128 + k8 * 8;
          int dst = chain * 256 + ((k8 * 16) ^ ((chain & 7) << 4));
          u32x4 p0a = *(const u32x4*)(s0G + srcOff);
          u32x4 p0b = *(const u32x4*)(s0G + srcOff + 4);
          u32x4 p1a = *(const u32x4*)(s1G + srcOff);
          u32x4 p1b = *(const u32x4*)(s1G + srcOff + 4);
          alignas(16) unsigned short t0h[8], t0l[8], t1h[8], t1l[8];
#pragma unroll
          for (int e = 0; e < 4; ++e) {
            t0h[e]     = (unsigned short)(p0a[e] & 0xffffu); t0l[e]     = (unsigned short)(p0a[e] >> 16);
            t0h[4 + e] = (unsigned short)(p0b[e] & 0xffffu); t0l[4 + e] = (unsigned short)(p0b[e] >> 16);
            t1h[e]     = (unsigned short)(p1a[e] & 0xffffu); t1l[e]     = (unsigned short)(p1a[e] >> 16);
            t1h[4 + e] = (unsigned short)(p1b[e] & 0xffffu); t1l[4 + e] = (unsigned short)(p1b[e] >> 16);
          }
          *(short8*)(sh0hi + dst) = *(const short8*)t0h;
          *(short8*)(sh0lo + dst) = *(const short8*)t0l;
          *(short8*)(sh1hi + dst) = *(const short8*)t1h;
          *(short8*)(sh1lo + dst) = *(const short8*)t1l;
        }
        __syncthreads();
#pragma unroll
        for (int i = 0; i < 3; ++i) {
          int j = wave + 8 * i;
          if (j < 18) {
            bool act = (j < 6) ? act0 : act1;
            if (act) {
              int jj = (j < 6) ? j : ((j < 12) ? j - 6 : j - 12);
              int t = jj >> 1, mt = jj & 1;
              const char* A = (j < 12) ? (t == 2 ? sh0lo : sh0hi) : (t == 2 ? sh1lo : sh1hi);
              int m = (j < 6) ? 0 : ((j < 12) ? 1 : 2);
              const char* Bp = (t == 1) ? (smem + 49152 + m * 16384) : (smem + m * 16384);
              int arow = mt * 16 + lr;
              const char* Abase = A + arow * 256;
              int aswz = (arow & 7) << 4;
              const char* Bbase = Bp + lr * 1024;
              int bswz = (lr & 7) << 4;
#pragma unroll
              for (int kk = 0; kk < 4; ++kk) {
                short8 a = *(const short8*)(Abase + ((kk * 64 + lq * 16) ^ aswz));
                short8 b = *(const short8*)(Bbase + ((c * 256 + kk * 64 + lq * 16) ^ bswz));
                acc[i] = mfmaH(a, b, acc[i]);
              }
            }
          }
        }
        __syncthreads();
      }

      // publish fp32 partials: gbuf[j][chain(=lq*4+e)][row(=lr)]
#pragma unroll
      for (int i = 0; i < 3; ++i) {
        int j = wave + 8 * i;
        if (j < 18) {
#pragma unroll
          for (int e = 0; e < 4; ++e)
            gbuf[j * 272 + (lq * 4 + e) * 17 + lr] = acc[i][e];
        }
      }
      __syncthreads();

      // elementwise cell update: tid<256 -> 1 (layer,chain,hcol) per thread.
      // h -> ring slot via atomic swap w/ return (at-LLC publish, R9-proven).
      if (tid < 256) {
        bool act = eL ? act1 : act0;
        if (act) {
          int s = eL ? (k - 1) : k;
          int mt = eCi >> 4, cl = eCi & 15;
          float g[4];
#pragma unroll
          for (int q = 0; q < 4; ++q) {
            int ro = q * 4 + eHc;
            float v = bias[eL * 16 + ro];
            if (eL == 0) {
#pragma unroll
              for (int t = 0; t < 3; ++t) v += gbuf[(t * 2 + mt) * 272 + cl * 17 + ro];
            } else {
#pragma unroll
              for (int u = 0; u < 6; ++u) v += gbuf[(6 + u * 2 + mt) * 272 + cl * 17 + ro];
            }
            g[q] = v;
          }
          creg = sigm(g[1]) * creg + sigm(g[0]) * tanh_(g[2]);
          float h = sigm(g[3]) * tanh_(creg);
          f16 hhv = (f16)h;
          f16 hlv = (f16)(h - (float)hhv);
          u32 packed = (u32)h2u(hhv) | ((u32)h2u(hlv) << 16);
          u32* dst = (eL ? w1G : w0G) + eCi * 512 + hc0 + eHc;
          st_h_swap(dst, packed);
          if (eL && phase) d1[((bbase + eCi) * TT + s) * HH + hc0 + eHc] = h2u(hhv);
        }
      }
      __syncthreads();  // per-wave vmcnt drain: swap returns arrived -> data at LLC

      // group barrier: relaxed add on 32 line-isolated sub-counters (4-deep
      // RMW convoy instead of 16-deep), relaxed spin on the monotone sum.
      __builtin_amdgcn_sched_barrier(0);
      if (tid == 0) {
        __hip_atomic_fetch_add(mycnt + (slot & 31) * 16, 1, __ATOMIC_RELAXED, __HIP_MEMORY_SCOPE_AGENT);
        int target = 128 * (phase * (TT + 1) + k + 1);
        long guard = 0;
        for (;;) {
          int sum = 0;
#pragma unroll
          for (int jj = 0; jj < 32; ++jj)
            sum += __hip_atomic_load(mycnt + jj * 16, __ATOMIC_RELAXED, __HIP_MEMORY_SCOPE_AGENT);
          if (sum >= target) break;
          if (++guard > (1L << 26)) break;   // anti-deadlock bail (turns hang into wrong-answer)
        }
      }
      __syncthreads();
    }
  }
}

__global__ __launch_bounds__(256, 1)
void outproj_kernel(const unsigned short* __restrict__ d1, const float* __restrict__ out_w,
                    const float* __restrict__ out_b, float* __restrict__ out) {
  extern __shared__ char smem[];
  const int tid = threadIdx.x;
#pragma unroll
  for (int i = 0; i < 16; ++i) {  // out_w [51][512] -> LDS [64][512] fp16 swizzled
    int task = tid + i * 256;
    int c8 = task & 63;
    int r = task >> 6;
    alignas(16) unsigned short tmp[8];
    if (r < FF) {
      const float* src = out_w + r * HH + c8 * 8;
#pragma unroll
      for (int e = 0; e < 8; ++e) tmp[e] = h2u((f16)src[e]);
    } else {
#pragma unroll
      for (int e = 0; e < 8; ++e) tmp[e] = 0;
    }
    *(short8*)(smem + r * 1024 + ((c8 * 16) ^ ((r & 7) << 4))) = *(const short8*)tmp;
  }
  __syncthreads();
  const int wave = tid >> 6, lane = tid & 63;
  const int lr = lane & 15, lq = lane >> 4;
  const int r0 = blockIdx.x * 64 + wave * 16;   // row in [B*T, H] view of d1
  f32x4 acc0 = {0.f, 0.f, 0.f, 0.f}, acc1 = acc0, acc2 = acc0, acc3 = acc0;
  const unsigned short* ap = d1 + (r0 + lr) * HH + lq * 8;
#pragma unroll
  for (int kk = 0; kk < 16; ++kk) {
    short8 a = *(const short8*)(ap + kk * 32);
    int kb = kk * 64 + lq * 16;
    acc0 = mfmaH(a, *(const short8*)(smem + (0 + lr) * 1024 + (kb ^ ((lr & 7) << 4))), acc0);
    acc1 = mfmaH(a, *(const short8*)(smem + (16 + lr) * 1024 + (kb ^ ((lr & 7) << 4))), acc1);
    acc2 = mfmaH(a, *(const short8*)(smem + (32 + lr) * 1024 + (kb ^ ((lr & 7) << 4))), acc2);
    acc3 = mfmaH(a, *(const short8*)(smem + (48 + lr) * 1024 + (kb ^ ((lr & 7) << 4))), acc3);
  }
  f32x4 accs[4] = {acc0, acc1, acc2, acc3};
#pragma unroll
  for (int nt = 0; nt < 4; ++nt) {
    int col = nt * 16 + lr;
    if (col < FF) {
      float bb = out_b[col];
#pragma unroll
      for (int e = 0; e < 4; ++e) {
        int row = r0 + lq * 4 + e;
        out[row * FF + col] = accs[nt][e] + bb;
      }
    }
  }
}

extern "C" void kernel_launch(void* const* d_in, const int* in_sizes, int n_in,
                              void* d_out, int out_size, void* d_ws, size_t ws_size,
                              hipStream_t stream) {
  const float* x = (const float*)d_in[0];
  const float* ew_ih0 = (const float*)d_in[1];
  const float* ew_hh0 = (const float*)d_in[2];
  const float* eb_ih0 = (const float*)d_in[3];
  const float* eb_hh0 = (const float*)d_in[4];
  const float* ew_ih1 = (const float*)d_in[5];
  const float* ew_hh1 = (const float*)d_in[6];
  const float* eb_ih1 = (const float*)d_in[7];
  const float* eb_hh1 = (const float*)d_in[8];
  const float* dw_ih0 = (const float*)d_in[9];
  const float* dw_hh0 = (const float*)d_in[10];
  const float* db_ih0 = (const float*)d_in[11];
  const float* db_hh0 = (const float*)d_in[12];
  const float* dw_ih1 = (const float*)d_in[13];
  const float* dw_hh1 = (const float*)d_in[14];
  const float* db_ih1 = (const float*)d_in[15];
  const float* db_hh1 = (const float*)d_in[16];
  const float* out_w = (const float*)d_in[17];
  const float* out_b = (const float*)d_in[18];

  char* ws = (char*)d_ws;
  int* cnt = (int*)(ws + OFF_CNT);
  u32* ring = (u32*)(ws + OFF_RING);
  unsigned short* xhi = (unsigned short*)(ws + OFF_XHI);
  unsigned short* xlo = (unsigned short*)(ws + OFF_XLO);
  unsigned short* d1 = (unsigned short*)(ws + OFF_D1);

  (void)hipFuncSetAttribute((const void*)lstm_kernel, hipFuncAttributeMaxDynamicSharedMemorySize, 154944);
  (void)hipFuncSetAttribute((const void*)outproj_kernel, hipFuncAttributeMaxDynamicSharedMemorySize, 65536);

  init_kernel<<<1024, 256, 0, stream>>>(x, xhi, xlo, ring, cnt);
  lstm_kernel<<<256, 512, 154944, stream>>>(ew_ih0, ew_hh0, eb_ih0, eb_hh0,
                                            ew_ih1, ew_hh1, eb_ih1, eb_hh1,
                                            dw_ih0, dw_hh0, db_ih0, db_hh0,
                                            dw_ih1, dw_hh1, db_ih1, db_hh1,
                                            ring, xhi, xlo, d1, cnt);
  outproj_kernel<<<512, 256, 65536, stream>>>(d1, out_w, out_b, (float*)d_out);
}